// Round 1
// baseline (219.645 us; speedup 1.0000x reference)
//
#include <hip/hip_runtime.h>

// B=2, L=2048, DIM=1024, H=16, HD=64; scale folded into Q: 0.125*log2e; mask: -60*log2e
#define LL 2048
#define NHEADS 16
#define HDIM 64
#define QSCALE 0.18033688011112042f   // 0.125 * log2(e)
#define MASKC1 -86.56170245333780f    // -60 * log2(e)

typedef __attribute__((ext_vector_type(8))) __bf16 bf16x8;
typedef __attribute__((ext_vector_type(4))) float f32x4;

__device__ __forceinline__ unsigned short f2bf(float f) {
  unsigned int u = __builtin_bit_cast(unsigned int, f);
  u += 0x7fffu + ((u >> 16) & 1u);   // RNE
  return (unsigned short)(u >> 16);
}

__device__ __forceinline__ bf16x8 ld_frag(const unsigned short* p) {
  return *reinterpret_cast<const bf16x8*>(p);
}

// async global->LDS, 16B per lane; LDS dest = wave-uniform base + lane*16
__device__ __forceinline__ void async_cp16(const unsigned short* g, unsigned short* l) {
  __builtin_amdgcn_global_load_lds(
      (const __attribute__((address_space(1))) unsigned int*)(unsigned long long)(g),
      (__attribute__((address_space(3))) unsigned int*)(unsigned int)(unsigned long long)(l),
      16, 0, 0);
}

// ---------------- prep: fp32 -> bf16 convert of x ----------------
__global__ __launch_bounds__(256) void cvt_x_kernel(const float* __restrict__ x,
                                                    unsigned short* __restrict__ xb) {
  int i = (blockIdx.x * 256 + threadIdx.x) * 4;
  float4 v = *reinterpret_cast<const float4*>(x + i);
  ushort4 o;
  o.x = f2bf(v.x); o.y = f2bf(v.y); o.z = f2bf(v.z); o.w = f2bf(v.w);
  *reinterpret_cast<ushort4*>(xb + i) = o;
}

// ---------------- prep: W [K][N] fp32 -> Wt [N][K] bf16 ----------------
__global__ __launch_bounds__(256) void transpose_w_kernel(const float* __restrict__ Wq,
                                                          const float* __restrict__ Wk,
                                                          const float* __restrict__ Wv,
                                                          unsigned short* __restrict__ WtAll) {
  int z = blockIdx.z;
  const float* W = (z == 0) ? Wq : (z == 1) ? Wk : Wv;
  unsigned short* dst = WtAll + (size_t)z * 1024 * 1024;
  int n0 = blockIdx.x * 64, k0 = blockIdx.y * 64;
  __shared__ float t[64][65];
  int tx = threadIdx.x & 63, ty = threadIdx.x >> 6;
#pragma unroll
  for (int p = 0; p < 16; ++p) {
    int kr = p * 4 + ty;
    t[kr][tx] = W[(size_t)(k0 + kr) * 1024 + n0 + tx];
  }
  __syncthreads();
#pragma unroll
  for (int p = 0; p < 16; ++p) {
    int nr = p * 4 + ty;
    dst[(size_t)(n0 + nr) * 1024 + k0 + tx] = f2bf(t[tx][nr]);
  }
}

// ---------------- prep: lem = bf16(mask*MASKC1), per-flash-thread swizzled ----------------
// Layout: [b][qblk(32)][kt(32)][tid(256)][16 shorts = 32B]:
//   thread (w,g,cc)'s 32B = for nt=0..3: 4 bf16 lem[q = qblk*64 + w*16 + g*4 + j][k = kt*64 + nt*16 + cc]
// Flash inits its QK accumulators from these (mask folded into MFMA C-in).
__global__ __launch_bounds__(256) void lem_prep_kernel(const float* __restrict__ mask,
                                                       unsigned short* __restrict__ lem) {
  const int qb = blockIdx.x, kt = blockIdx.y, b = blockIdx.z;
  const int tid = threadIdx.x;
  const int w = tid >> 6, lane = tid & 63, g = lane >> 4, cc = lane & 15;
  const float* src = mask + ((size_t)b * LL + qb * 64 + w * 16 + g * 4) * LL + kt * 64 + cc;
  unsigned int u[8];
#pragma unroll
  for (int nt = 0; nt < 4; ++nt) {
    unsigned short h0 = f2bf(src[0 * LL + nt * 16] * MASKC1);
    unsigned short h1 = f2bf(src[1 * LL + nt * 16] * MASKC1);
    unsigned short h2 = f2bf(src[2 * LL + nt * 16] * MASKC1);
    unsigned short h3 = f2bf(src[3 * LL + nt * 16] * MASKC1);
    u[nt * 2]     = (unsigned int)h0 | ((unsigned int)h1 << 16);
    u[nt * 2 + 1] = (unsigned int)h2 | ((unsigned int)h3 << 16);
  }
  uint4* dst = reinterpret_cast<uint4*>(
      lem + ((((size_t)b * 32 + qb) * 32 + kt) * 256 + tid) * 16);
  dst[0] = make_uint4(u[0], u[1], u[2], u[3]);
  dst[1] = make_uint4(u[4], u[5], u[6], u[7]);
}

// ---------------- QKV projection GEMM (m97-style async staging, swizzled rows) ----------------
// grid (8, 32, 3). z==0: Q bf16 [bh][l][d] * QSCALE; z==1: K; z==2: V^T [bh][d][l], pos-permuted.
__global__ __launch_bounds__(256) void qkv_gemm_kernel(
    const unsigned short* __restrict__ xb, const unsigned short* __restrict__ WtAll,
    const float* __restrict__ bq, const float* __restrict__ bk, const float* __restrict__ bv,
    unsigned short* __restrict__ qkv) {
  const int z = blockIdx.z;
  const unsigned short* Wt = WtAll + (size_t)z * 1024 * 1024;
  const float* bias = (z == 0) ? bq : (z == 1) ? bk : bv;
  unsigned short* outb = qkv + (size_t)z * 4194304;

  __shared__ __align__(16) unsigned short smem[16384];  // As 8192, Bs 8192 (stride 64, swizzled)
  unsigned short* As = smem;
  unsigned short* Bs = smem + 8192;

  const int tid = threadIdx.x;
  const int w = tid >> 6, lane = tid & 63, g = lane >> 4, cc = lane & 15;
  const int wm = w >> 1, wn = w & 1;
  const int m0 = blockIdx.y * 128, n0 = blockIdx.x * 128;
  // async staging: wave w stages A/B rows [w*32, w*32+32) as 4 segs of 8 rows.
  const int srow = lane >> 3;                 // row within seg
  const int gc = ((lane & 7) - srow) & 7;     // swizzle: LDS slot s holds chunk (s - row)&7
  const unsigned short* ga = xb + (size_t)(m0 + w * 32 + srow) * 1024 + gc * 8;
  const unsigned short* gb = Wt + (size_t)(n0 + w * 32 + srow) * 1024 + gc * 8;
  unsigned short* la = As + w * 2048;   // 4 segs * 512
  unsigned short* lb = Bs + w * 2048;

  f32x4 acc[4][4];
#pragma unroll
  for (int i = 0; i < 4; ++i)
#pragma unroll
    for (int j = 0; j < 4; ++j) acc[i][j] = (f32x4)0.0f;

  for (int kk = 0; kk < 1024; kk += 64) {
    __syncthreads();
#pragma unroll
    for (int i = 0; i < 4; ++i) {
      async_cp16(ga + i * 8192 + kk, la + i * 512);
      async_cp16(gb + i * 8192 + kk, lb + i * 512);
    }
    __syncthreads();  // compiler emits vmcnt(0) drain before barrier
    bf16x8 af[4][2], bfr[4][2];
#pragma unroll
    for (int mt = 0; mt < 4; ++mt)
#pragma unroll
      for (int ks = 0; ks < 2; ++ks)
        af[mt][ks] = ld_frag(&As[(wm * 64 + mt * 16 + cc) * 64 + ((4 * ks + g + cc) & 7) * 8]);
#pragma unroll
    for (int nt = 0; nt < 4; ++nt)
#pragma unroll
      for (int ks = 0; ks < 2; ++ks)
        bfr[nt][ks] = ld_frag(&Bs[(wn * 64 + nt * 16 + cc) * 64 + ((4 * ks + g + cc) & 7) * 8]);
#pragma unroll
    for (int mt = 0; mt < 4; ++mt)
#pragma unroll
      for (int nt = 0; nt < 4; ++nt)
#pragma unroll
        for (int ks = 0; ks < 2; ++ks)
          acc[mt][nt] = __builtin_amdgcn_mfma_f32_16x16x32_bf16(af[mt][ks], bfr[nt][ks],
                                                                acc[mt][nt], 0, 0, 0);
  }

  if (z != 2) {
    const float sc = (z == 0) ? QSCALE : 1.0f;
#pragma unroll
    for (int nt = 0; nt < 4; ++nt) {
      int n = n0 + wn * 64 + nt * 16 + cc;
      float bval = bias[n];
      int h = n >> 6, d = n & 63;
#pragma unroll
      for (int mt = 0; mt < 4; ++mt) {
#pragma unroll
        for (int r = 0; r < 4; ++r) {
          int m = m0 + wm * 64 + mt * 16 + g * 4 + r;
          int b = m >> 11, l = m & 2047;
          outb[(((size_t)(b * NHEADS + h) * LL) + l) * HDIM + d] =
              f2bf((acc[mt][nt][r] + bval) * sc);
        }
      }
    }
  } else {
    // V^T epilogue with key permutation pos = 4c + q (c = local&15, q = local>>4):
    // local = mt*16 + g*4 + r  ->  pos = 16g + 4r + mt
    __syncthreads();
#pragma unroll
    for (int nt = 0; nt < 4; ++nt) {
      int nr = wn * 64 + nt * 16 + cc;
      float bval = bias[n0 + nr];
#pragma unroll
      for (int mt = 0; mt < 4; ++mt)
#pragma unroll
        for (int r = 0; r < 4; ++r)
          smem[nr * 128 + wm * 64 + 16 * g + 4 * r + mt] = f2bf(acc[mt][nt][r] + bval);
    }
    __syncthreads();
    int row = tid >> 1, half = tid & 1;
    int n = n0 + row, hh = n >> 6, dd = n & 63;
    int bb = m0 >> 11, l0 = (m0 & 2047) + half * 64;
    unsigned short* dst = outb + ((size_t)(bb * NHEADS + hh) * HDIM + dd) * LL + l0;
#pragma unroll
    for (int i = 0; i < 8; ++i)
      *reinterpret_cast<uint4*>(dst + i * 8) =
          *reinterpret_cast<const uint4*>(&smem[row * 128 + half * 64 + i * 8]);
  }
}

// ---------------- flash attention ----------------
// grid (32, 32), 64 q-rows/block, 16 q-rows/wave. 4 blocks/CU (LDS = 40960 B exactly).
// Mask folded into MFMA acc-init (lem, pre-swizzled per-thread). One barrier/kt,
// ping-pong K/V via global_load_lds (swizzled rows). Ps: stride-64 + XOR-chunk swizzle.
__global__ __launch_bounds__(256, 4) void flash_kernel(
    const unsigned short* __restrict__ Qb, const unsigned short* __restrict__ Kb,
    const unsigned short* __restrict__ Vt, const unsigned short* __restrict__ Lem,
    float* __restrict__ out) {
  // bijective XCD swizzle: 1024 blocks, 8 XCDs -> each XCD keeps 4 bh (2MB K/V) L2-resident
  const int id = blockIdx.y * 32 + blockIdx.x;
  const int nid = (id & 7) * 128 + (id >> 3);
  const int qb = nid & 31, bh = nid >> 5;
  const int b = bh >> 4, h = bh & 15;
  const int q0 = qb * 64;
  const int tid = threadIdx.x, w = tid >> 6, lane = tid & 63, g = lane >> 4, cc = lane & 15;
  const size_t bhoff = (size_t)bh * LL * HDIM;

  __shared__ __align__(16) unsigned short Ps[64 * 64];     // 8KB, XOR-swizzled chunks
  __shared__ __align__(16) unsigned short Ks[2][64 * 64];  // 16KB, [key][d] swizzled chunks
  __shared__ __align__(16) unsigned short Vs[2][64 * 64];  // 16KB, [d][pos] swizzled chunks

  // Q fragments straight from global (loop-invariant): 16 rows per wave
  bf16x8 aq[2];
#pragma unroll
  for (int ks = 0; ks < 2; ++ks)
    aq[ks] = *reinterpret_cast<const bf16x8*>(
        Qb + bhoff + (size_t)(q0 + w * 16 + cc) * HDIM + ks * 32 + g * 8);

  // async staging: wave w stages K segs {w, w+4} and V segs {w, w+4}
  const int srow = lane >> 3;
  const int gcs = ((lane & 7) - srow) & 7;
  const unsigned short* kg0 = Kb + bhoff + (size_t)(w * 8 + srow) * HDIM + gcs * 8;
  const unsigned short* kg1 = Kb + bhoff + (size_t)(32 + w * 8 + srow) * HDIM + gcs * 8;
  const unsigned short* vg0 = Vt + bhoff + (size_t)(w * 8 + srow) * LL + gcs * 8;
  const unsigned short* vg1 = Vt + bhoff + (size_t)(32 + w * 8 + srow) * LL + gcs * 8;

  // per-thread lem stream: 32B per kt, contiguous
  const uint4* lemp = reinterpret_cast<const uint4*>(
      Lem + ((((size_t)b * 32 + qb) * 32 + 0) * 256 + tid) * 16);

  float li[4];
  f32x4 oacc[4];
#pragma unroll
  for (int r = 0; r < 4; ++r) li[r] = 0.0f;
#pragma unroll
  for (int nt = 0; nt < 4; ++nt) oacc[nt] = (f32x4)0.0f;

  // stage tile 0 into buf 0
  {
    async_cp16(kg0, Ks[0] + w * 512);
    async_cp16(kg1, Ks[0] + (w + 4) * 512);
    async_cp16(vg0, Vs[0] + w * 512);
    async_cp16(vg1, Vs[0] + (w + 4) * 512);
  }

  for (int kt = 0; kt < 32; ++kt) {
    const int buf = kt & 1;
    __syncthreads();  // drains own asyncs (vmcnt 0) -> tile kt ready; prior reads of buf^1 done
    if (kt + 1 < 32) {
      const int nb = buf ^ 1;
      async_cp16(kg0 + (size_t)(kt + 1) * 64 * HDIM, Ks[nb] + w * 512);
      async_cp16(kg1 + (size_t)(kt + 1) * 64 * HDIM, Ks[nb] + (w + 4) * 512);
      async_cp16(vg0 + (kt + 1) * 64, Vs[nb] + w * 512);
      async_cp16(vg1 + (kt + 1) * 64, Vs[nb] + (w + 4) * 512);
    }
    // lem: two 16B loads from one base; init sacc with the log-domain mask (C-in of MFMA)
    uint4 e0 = lemp[0], e1 = lemp[1];
    lemp += 512;  // 8192 B per kt
    f32x4 sacc[4];
    {
      unsigned int ux, uy;
      ux = e0.x; uy = e0.y;
      sacc[0][0] = __builtin_bit_cast(float, ux << 16);
      sacc[0][1] = __builtin_bit_cast(float, ux & 0xffff0000u);
      sacc[0][2] = __builtin_bit_cast(float, uy << 16);
      sacc[0][3] = __builtin_bit_cast(float, uy & 0xffff0000u);
      ux = e0.z; uy = e0.w;
      sacc[1][0] = __builtin_bit_cast(float, ux << 16);
      sacc[1][1] = __builtin_bit_cast(float, ux & 0xffff0000u);
      sacc[1][2] = __builtin_bit_cast(float, uy << 16);
      sacc[1][3] = __builtin_bit_cast(float, uy & 0xffff0000u);
      ux = e1.x; uy = e1.y;
      sacc[2][0] = __builtin_bit_cast(float, ux << 16);
      sacc[2][1] = __builtin_bit_cast(float, ux & 0xffff0000u);
      sacc[2][2] = __builtin_bit_cast(float, uy << 16);
      sacc[2][3] = __builtin_bit_cast(float, uy & 0xffff0000u);
      ux = e1.z; uy = e1.w;
      sacc[3][0] = __builtin_bit_cast(float, ux << 16);
      sacc[3][1] = __builtin_bit_cast(float, ux & 0xffff0000u);
      sacc[3][2] = __builtin_bit_cast(float, uy << 16);
      sacc[3][3] = __builtin_bit_cast(float, uy & 0xffff0000u);
    }

    // S = Q @ K^T + lem
    bf16x8 bk_[4][2];
#pragma unroll
    for (int nt = 0; nt < 4; ++nt)
#pragma unroll
      for (int ks = 0; ks < 2; ++ks)
        bk_[nt][ks] =
            ld_frag(&Ks[buf][(nt * 16 + cc) * 64 + ((4 * ks + g + cc) & 7) * 8]);
#pragma unroll
    for (int nt = 0; nt < 4; ++nt)
#pragma unroll
      for (int ks = 0; ks < 2; ++ks)
        sacc[nt] = __builtin_amdgcn_mfma_f32_16x16x32_bf16(aq[ks], bk_[nt][ks],
                                                           sacc[nt], 0, 0, 0);

    // p = exp2(s); pack 4 bf16 (truncation) -> one b64 store at pos 4cc (XOR-swizzled chunk)
#pragma unroll
    for (int r = 0; r < 4; ++r) {
      float p0 = __builtin_amdgcn_exp2f(sacc[0][r]);
      float p1 = __builtin_amdgcn_exp2f(sacc[1][r]);
      float p2 = __builtin_amdgcn_exp2f(sacc[2][r]);
      float p3 = __builtin_amdgcn_exp2f(sacc[3][r]);
      unsigned int u01 = __builtin_amdgcn_perm(__builtin_bit_cast(unsigned int, p1),
                                               __builtin_bit_cast(unsigned int, p0),
                                               0x07060302u);
      unsigned int u23 = __builtin_amdgcn_perm(__builtin_bit_cast(unsigned int, p3),
                                               __builtin_bit_cast(unsigned int, p2),
                                               0x07060302u);
      // li sums the truncated values so numerator/denominator stay consistent
      li[r] += __builtin_bit_cast(float, u01 << 16) +
               __builtin_bit_cast(float, u01 & 0xffff0000u) +
               __builtin_bit_cast(float, u23 << 16) +
               __builtin_bit_cast(float, u23 & 0xffff0000u);
      const int row = w * 16 + g * 4 + r;
      const int sidx = row * 64 + (((cc >> 1) ^ (row & 7)) << 3) + ((cc & 1) << 2);
      uint2 pk; pk.x = u01; pk.y = u23;
      *reinterpret_cast<uint2*>(&Ps[sidx]) = pk;
    }
    asm volatile("" ::: "memory");  // P stores before same-wave P frag reads

    // O += P @ V   (k-dim = pos, matches Vs column order)
    bf16x8 ap[2], bv[4][2];
#pragma unroll
    for (int ks = 0; ks < 2; ++ks)
      ap[ks] = ld_frag(&Ps[(w * 16 + cc) * 64 + (((ks * 4 + g) ^ (cc & 7)) << 3)]);
#pragma unroll
    for (int nt = 0; nt < 4; ++nt)
#pragma unroll
      for (int ks = 0; ks < 2; ++ks)
        bv[nt][ks] =
            ld_frag(&Vs[buf][(nt * 16 + cc) * 64 + ((4 * ks + g + cc) & 7) * 8]);
#pragma unroll
    for (int nt = 0; nt < 4; ++nt)
#pragma unroll
      for (int ks = 0; ks < 2; ++ks)
        oacc[nt] = __builtin_amdgcn_mfma_f32_16x16x32_bf16(ap[ks], bv[nt][ks],
                                                           oacc[nt], 0, 0, 0);
  }

  // epilogue: reduce li over cc-lanes, normalize, write [B, L, H*HD] fp32
#pragma unroll
  for (int r = 0; r < 4; ++r) {
    float s = li[r];
    s += __shfl_xor(s, 1);
    s += __shfl_xor(s, 2);
    s += __shfl_xor(s, 4);
    s += __shfl_xor(s, 8);
    float inv = 1.0f / s;
    int qrow = q0 + w * 16 + g * 4 + r;
#pragma unroll
    for (int nt = 0; nt < 4; ++nt)
      out[((size_t)b * LL + qrow) * 1024 + h * 64 + nt * 16 + cc] = oacc[nt][r] * inv;
  }
}

extern "C" void kernel_launch(void* const* d_in, const int* in_sizes, int n_in,
                              void* d_out, int out_size, void* d_ws, size_t ws_size,
                              hipStream_t stream) {
  const float* x    = (const float*)d_in[0];
  const float* mask = (const float*)d_in[1];
  const float* Wq   = (const float*)d_in[2];
  const float* bq   = (const float*)d_in[3];
  const float* Wk   = (const float*)d_in[4];
  const float* bk   = (const float*)d_in[5];
  const float* Wv   = (const float*)d_in[6];
  const float* bv   = (const float*)d_in[7];
  float* out = (float*)d_out;
  (void)in_sizes; (void)n_in; (void)out_size; (void)ws_size;

  char* ws = (char*)d_ws;
  // layout: qkv @0 (24 MiB); xb @24 (8 MiB); Wt @32 (6 MiB);
  // lem @24 (16 MiB) overlaps xb/Wt — dead after qkv_gemm (same-stream serialization)
  unsigned short* qkv = (unsigned short*)(ws);
  unsigned short* xb  = (unsigned short*)(ws + (24u << 20));
  unsigned short* Wt  = (unsigned short*)(ws + (32u << 20));
  unsigned short* lem = (unsigned short*)(ws + (24u << 20));

  cvt_x_kernel<<<dim3(4096), dim3(256), 0, stream>>>(x, xb);
  transpose_w_kernel<<<dim3(16, 16, 3), dim3(256), 0, stream>>>(Wq, Wk, Wv, Wt);
  qkv_gemm_kernel<<<dim3(8, 32, 3), dim3(256), 0, stream>>>(xb, Wt, bq, bk, bv, qkv);
  lem_prep_kernel<<<dim3(32, 32, 2), dim3(256), 0, stream>>>(mask, lem);
  flash_kernel<<<dim3(32, 32), dim3(256), 0, stream>>>(qkv, qkv + 4194304, qkv + 8388608,
                                                       lem, out);
}

// Round 3
// 208.083 us; speedup vs baseline: 1.0556x; 1.0556x over previous
//
#include <hip/hip_runtime.h>

// B=2, L=2048, DIM=1024, H=16, HD=64; scale folded into Q: 0.125*log2e; mask: -60*log2e
#define LL 2048
#define NHEADS 16
#define HDIM 64
#define QSCALE 0.18033688011112042f   // 0.125 * log2(e)
#define MASKC1 -86.56170245333780f    // -60 * log2(e)

typedef __attribute__((ext_vector_type(8))) __bf16 bf16x8;
typedef __attribute__((ext_vector_type(4))) float f32x4;
typedef __attribute__((ext_vector_type(4))) unsigned int u32x4;

__device__ __forceinline__ unsigned short f2bf(float f) {
  unsigned int u = __builtin_bit_cast(unsigned int, f);
  u += 0x7fffu + ((u >> 16) & 1u);   // RNE
  return (unsigned short)(u >> 16);
}

__device__ __forceinline__ bf16x8 ld_frag(const unsigned short* p) {
  return *reinterpret_cast<const bf16x8*>(p);
}

__device__ __forceinline__ float bflo(unsigned int u) {
  return __builtin_bit_cast(float, u << 16);
}
__device__ __forceinline__ float bfhi(unsigned int u) {
  return __builtin_bit_cast(float, u & 0xffff0000u);
}
// pack two floats (truncated to bf16) into one u32: low short = lo, high short = hi
__device__ __forceinline__ unsigned int pack2(float hi, float lo) {
  return __builtin_amdgcn_perm(__builtin_bit_cast(unsigned int, hi),
                               __builtin_bit_cast(unsigned int, lo), 0x07060302u);
}

// async global->LDS, 16B per lane; LDS dest = wave-uniform base + lane*16
__device__ __forceinline__ void async_cp16(const unsigned short* g, unsigned short* l) {
  __builtin_amdgcn_global_load_lds(
      (const __attribute__((address_space(1))) unsigned int*)(unsigned long long)(g),
      (__attribute__((address_space(3))) unsigned int*)(unsigned int)(unsigned long long)(l),
      16, 0, 0);
}

// ---------------- prep: fp32 -> bf16 convert of x ----------------
__global__ __launch_bounds__(256) void cvt_x_kernel(const float* __restrict__ x,
                                                    unsigned short* __restrict__ xb) {
  int i = (blockIdx.x * 256 + threadIdx.x) * 4;
  float4 v = *reinterpret_cast<const float4*>(x + i);
  ushort4 o;
  o.x = f2bf(v.x); o.y = f2bf(v.y); o.z = f2bf(v.z); o.w = f2bf(v.w);
  *reinterpret_cast<ushort4*>(xb + i) = o;
}

// ---------------- prep: W [K][N] fp32 -> Wt [N][K] bf16 ----------------
__global__ __launch_bounds__(256) void transpose_w_kernel(const float* __restrict__ Wq,
                                                          const float* __restrict__ Wk,
                                                          const float* __restrict__ Wv,
                                                          unsigned short* __restrict__ WtAll) {
  int z = blockIdx.z;
  const float* W = (z == 0) ? Wq : (z == 1) ? Wk : Wv;
  unsigned short* dst = WtAll + (size_t)z * 1024 * 1024;
  int n0 = blockIdx.x * 64, k0 = blockIdx.y * 64;
  __shared__ float t[64][65];
  int tx = threadIdx.x & 63, ty = threadIdx.x >> 6;
#pragma unroll
  for (int p = 0; p < 16; ++p) {
    int kr = p * 4 + ty;
    t[kr][tx] = W[(size_t)(k0 + kr) * 1024 + n0 + tx];
  }
  __syncthreads();
#pragma unroll
  for (int p = 0; p < 16; ++p) {
    int nr = p * 4 + ty;
    dst[(size_t)(n0 + nr) * 1024 + k0 + tx] = f2bf(t[tx][nr]);
  }
}

// ---------------- prep: lem = bf16(mask*MASKC1), per-flash-thread packed ----------------
// Output layout [b][qb(16)][kt(32)][tid(256)][32 shorts = 64B]; 32 shorts ordered
// idx = mt*16 + nt*4 + r  for value lem[q = qb*128 + w*32 + mt*16 + cc][k = kt*64 + nt*16 + g*4 + r].
// Coalesced float4 reads -> LDS bf16 tile [128][72] -> b64 gather (r-pairs adjacent in k).
__global__ __launch_bounds__(256) void lem_prep_kernel(const float* __restrict__ mask,
                                                       unsigned short* __restrict__ lem) {
  const int qb = blockIdx.x, kt = blockIdx.y, b = blockIdx.z;
  const int tid = threadIdx.x;
  __shared__ unsigned short lds[128 * 72];
  {
    const int r0 = tid >> 4;          // 0..15
    const int c0 = (tid & 15) * 4;    // 0..60
#pragma unroll
    for (int p = 0; p < 8; ++p) {
      int row = p * 16 + r0;
      float4 v = *reinterpret_cast<const float4*>(
          mask + ((size_t)b * LL + qb * 128 + row) * LL + kt * 64 + c0);
      ushort4 o;
      o.x = f2bf(v.x * MASKC1); o.y = f2bf(v.y * MASKC1);
      o.z = f2bf(v.z * MASKC1); o.w = f2bf(v.w * MASKC1);
      *reinterpret_cast<ushort4*>(&lds[row * 72 + c0]) = o;
    }
  }
  __syncthreads();
  const int w = tid >> 6, lane = tid & 63, g = lane >> 4, cc = lane & 15;
  unsigned int ow[16];
#pragma unroll
  for (int mt = 0; mt < 2; ++mt) {
    const int q = w * 32 + mt * 16 + cc;
#pragma unroll
    for (int nt = 0; nt < 4; ++nt) {
      uint2 v = *reinterpret_cast<const uint2*>(&lds[q * 72 + nt * 16 + g * 4]);
      ow[mt * 8 + nt * 2]     = v.x;   // r0 (lo), r1 (hi)
      ow[mt * 8 + nt * 2 + 1] = v.y;   // r2 (lo), r3 (hi)
    }
  }
  uint4* dst = reinterpret_cast<uint4*>(
      lem + ((((size_t)b * 16 + qb) * 32 + kt) * 256 + tid) * 32);
#pragma unroll
  for (int j = 0; j < 4; ++j)
    dst[j] = make_uint4(ow[4 * j], ow[4 * j + 1], ow[4 * j + 2], ow[4 * j + 3]);
}

// ---------------- QKV projection GEMM (m97-style async staging, swizzled rows) ----------------
// grid (8, 32, 3). z==0: Q bf16 [bh][l][d] * QSCALE; z==1: K; z==2: V^T [bh][d][pos], key-permuted
// with pos(key6) = (key6>>5)*32 + ((key6>>2)&3)*8 + ((key6>>4)&1)*4 + (key6&3).
__global__ __launch_bounds__(256) void qkv_gemm_kernel(
    const unsigned short* __restrict__ xb, const unsigned short* __restrict__ WtAll,
    const float* __restrict__ bq, const float* __restrict__ bk, const float* __restrict__ bv,
    unsigned short* __restrict__ qkv) {
  const int z = blockIdx.z;
  const unsigned short* Wt = WtAll + (size_t)z * 1024 * 1024;
  const float* bias = (z == 0) ? bq : (z == 1) ? bk : bv;
  unsigned short* outb = qkv + (size_t)z * 4194304;

  __shared__ __align__(16) unsigned short smem[16384];  // As 8192, Bs 8192 (stride 64, swizzled)
  unsigned short* As = smem;
  unsigned short* Bs = smem + 8192;

  const int tid = threadIdx.x;
  const int w = tid >> 6, lane = tid & 63, g = lane >> 4, cc = lane & 15;
  const int wm = w >> 1, wn = w & 1;
  const int m0 = blockIdx.y * 128, n0 = blockIdx.x * 128;
  const int srow = lane >> 3;                 // row within seg
  const int gc = ((lane & 7) - srow) & 7;     // swizzle: LDS slot s holds chunk (s - row)&7
  const unsigned short* ga = xb + (size_t)(m0 + w * 32 + srow) * 1024 + gc * 8;
  const unsigned short* gb = Wt + (size_t)(n0 + w * 32 + srow) * 1024 + gc * 8;
  unsigned short* la = As + w * 2048;   // 4 segs * 512
  unsigned short* lb = Bs + w * 2048;

  f32x4 acc[4][4];
#pragma unroll
  for (int i = 0; i < 4; ++i)
#pragma unroll
    for (int j = 0; j < 4; ++j) acc[i][j] = (f32x4)0.0f;

  for (int kk = 0; kk < 1024; kk += 64) {
    __syncthreads();
#pragma unroll
    for (int i = 0; i < 4; ++i) {
      async_cp16(ga + i * 8192 + kk, la + i * 512);
      async_cp16(gb + i * 8192 + kk, lb + i * 512);
    }
    __syncthreads();  // compiler emits vmcnt(0) drain before barrier
    bf16x8 af[4][2], bfr[4][2];
#pragma unroll
    for (int mt = 0; mt < 4; ++mt)
#pragma unroll
      for (int ks = 0; ks < 2; ++ks)
        af[mt][ks] = ld_frag(&As[(wm * 64 + mt * 16 + cc) * 64 + ((4 * ks + g + cc) & 7) * 8]);
#pragma unroll
    for (int nt = 0; nt < 4; ++nt)
#pragma unroll
      for (int ks = 0; ks < 2; ++ks)
        bfr[nt][ks] = ld_frag(&Bs[(wn * 64 + nt * 16 + cc) * 64 + ((4 * ks + g + cc) & 7) * 8]);
#pragma unroll
    for (int mt = 0; mt < 4; ++mt)
#pragma unroll
      for (int nt = 0; nt < 4; ++nt)
#pragma unroll
        for (int ks = 0; ks < 2; ++ks)
          acc[mt][nt] = __builtin_amdgcn_mfma_f32_16x16x32_bf16(af[mt][ks], bfr[nt][ks],
                                                                acc[mt][nt], 0, 0, 0);
  }

  if (z != 2) {
    const float sc = (z == 0) ? QSCALE : 1.0f;
#pragma unroll
    for (int nt = 0; nt < 4; ++nt) {
      int n = n0 + wn * 64 + nt * 16 + cc;
      float bval = bias[n];
      int h = n >> 6, d = n & 63;
#pragma unroll
      for (int mt = 0; mt < 4; ++mt) {
#pragma unroll
        for (int r = 0; r < 4; ++r) {
          int m = m0 + wm * 64 + mt * 16 + g * 4 + r;
          int b = m >> 11, l = m & 2047;
          outb[(((size_t)(b * NHEADS + h) * LL) + l) * HDIM + d] =
              f2bf((acc[mt][nt][r] + bval) * sc);
        }
      }
    }
  } else {
    // V^T epilogue with key permutation: key6 = mt*16 + g*4 + r
    // -> pos = (mt>>1)*32 + g*8 + (mt&1)*4 + r   (inverse of flash's in-register P layout)
    __syncthreads();
#pragma unroll
    for (int nt = 0; nt < 4; ++nt) {
      int nr = wn * 64 + nt * 16 + cc;
      float bval = bias[n0 + nr];
#pragma unroll
      for (int mt = 0; mt < 4; ++mt)
#pragma unroll
        for (int r = 0; r < 4; ++r)
          smem[nr * 128 + wm * 64 + (mt >> 1) * 32 + g * 8 + (mt & 1) * 4 + r] =
              f2bf(acc[mt][nt][r] + bval);
    }
    __syncthreads();
    int row = tid >> 1, half = tid & 1;
    int n = n0 + row, hh = n >> 6, dd = n & 63;
    int bb = m0 >> 11, l0 = (m0 & 2047) + half * 64;
    unsigned short* dst = outb + ((size_t)(bb * NHEADS + hh) * HDIM + dd) * LL + l0;
#pragma unroll
    for (int i = 0; i < 8; ++i)
      *reinterpret_cast<uint4*>(dst + i * 8) =
          *reinterpret_cast<const uint4*>(&smem[row * 128 + half * 64 + i * 8]);
  }
}

// ---------------- flash attention ----------------
// grid (16, 32): q-tile 128, 4 waves x 32 q-rows, 2 blocks/CU. Swapped QK^T (S^T = K*Q^T)
// puts P lane-local (q = cc) -> P packs straight into in-register PV A-frags via the
// key-permuted V^T; no P LDS buffer at all. lem folded into MFMA C-init.
// Per wave-kt LDS: 8 K-frag + 8 V-frag ds_read_b128 only (~49K cyc/CU total).
__global__ __launch_bounds__(256, 2) void flash_kernel(
    const unsigned short* __restrict__ Qb, const unsigned short* __restrict__ Kb,
    const unsigned short* __restrict__ Vt, const unsigned short* __restrict__ Lem,
    float* __restrict__ out) {
  const int id = blockIdx.y * 16 + blockIdx.x;   // 512 blocks
  const int nid = (id & 7) * 64 + (id >> 3);     // bijective XCD swizzle (512 % 8 == 0)
  const int qb = nid & 15, bh = nid >> 4;
  const int b = bh >> 4, h = bh & 15;
  const int q0 = qb * 128;
  const int tid = threadIdx.x, w = tid >> 6, lane = tid & 63, g = lane >> 4, cc = lane & 15;
  const size_t bhoff = (size_t)bh * LL * HDIM;

  __shared__ __align__(16) unsigned short Ks[2][64 * 64];  // [key][d], swizzled chunks
  __shared__ __align__(16) unsigned short Vs[2][64 * 64];  // [d][pos], swizzled chunks

  // Q fragments (B operand of swapped QK^T): lane (g,cc) holds Q[q0+w*32+mt*16+cc][ks*32+g*8..]
  bf16x8 aq[2][2];
#pragma unroll
  for (int mt = 0; mt < 2; ++mt)
#pragma unroll
    for (int ks = 0; ks < 2; ++ks)
      aq[mt][ks] = *reinterpret_cast<const bf16x8*>(
          Qb + bhoff + (size_t)(q0 + w * 32 + mt * 16 + cc) * HDIM + ks * 32 + g * 8);

  // async staging: wave w stages K segs {w, w+4} and V segs {w, w+4}
  const int srow = lane >> 3;
  const int gcs = ((lane & 7) - srow) & 7;
  const unsigned short* kg0 = Kb + bhoff + (size_t)(w * 8 + srow) * HDIM + gcs * 8;
  const unsigned short* kg1 = Kb + bhoff + (size_t)(32 + w * 8 + srow) * HDIM + gcs * 8;
  const unsigned short* vg0 = Vt + bhoff + (size_t)(w * 8 + srow) * LL + gcs * 8;
  const unsigned short* vg1 = Vt + bhoff + (size_t)(32 + w * 8 + srow) * LL + gcs * 8;

  // per-thread lem stream: 64B per kt, contiguous
  const uint4* lemp = reinterpret_cast<const uint4*>(
      Lem + (((size_t)b * 16 + qb) * 32 * 256 + tid) * 32);

  float li[2] = {0.0f, 0.0f};
  f32x4 oacc[2][4];
#pragma unroll
  for (int mt = 0; mt < 2; ++mt)
#pragma unroll
    for (int nt = 0; nt < 4; ++nt) oacc[mt][nt] = (f32x4)0.0f;

  // stage tile 0 into buf 0
  {
    async_cp16(kg0, Ks[0] + w * 512);
    async_cp16(kg1, Ks[0] + (w + 4) * 512);
    async_cp16(vg0, Vs[0] + w * 512);
    async_cp16(vg1, Vs[0] + (w + 4) * 512);
  }

  for (int kt = 0; kt < 32; ++kt) {
    const int buf = kt & 1;
    __syncthreads();  // drains own asyncs (vmcnt 0) -> tile kt ready; prior reads of buf^1 done
    if (kt + 1 < 32) {
      const int nb = buf ^ 1;
      async_cp16(kg0 + (size_t)(kt + 1) * 64 * HDIM, Ks[nb] + w * 512);
      async_cp16(kg1 + (size_t)(kt + 1) * 64 * HDIM, Ks[nb] + (w + 4) * 512);
      async_cp16(vg0 + (kt + 1) * 64, Vs[nb] + w * 512);
      async_cp16(vg1 + (kt + 1) * 64, Vs[nb] + (w + 4) * 512);
    }
    uint4 e0 = lemp[0], e1 = lemp[1], e2 = lemp[2], e3 = lemp[3];
    lemp += 1024;  // 16 KB per kt

    // K fragments (A operand): lane (cc,g) holds K[nt*16+cc][ks*32+g*8..]; shared by both mt
    bf16x8 bk_[4][2];
#pragma unroll
    for (int nt = 0; nt < 4; ++nt)
#pragma unroll
      for (int ks = 0; ks < 2; ++ks)
        bk_[nt][ks] =
            ld_frag(&Ks[buf][(nt * 16 + cc) * 64 + ((4 * ks + g + cc) & 7) * 8]);
    // V fragments (B operand of PV), issued early to keep the LDS pipe busy under softmax
    bf16x8 bv[4][2];
#pragma unroll
    for (int nt = 0; nt < 4; ++nt)
#pragma unroll
      for (int ks = 0; ks < 2; ++ks)
        bv[nt][ks] =
            ld_frag(&Vs[buf][(nt * 16 + cc) * 64 + ((4 * ks + g + cc) & 7) * 8]);

    bf16x8 ap[2][2];
#pragma unroll
    for (int mt = 0; mt < 2; ++mt) {
      // S^T tile: sacc[nt] lane (cc,g) = S[key nt*16+g*4+r][q = w*32+mt*16+cc], C-init = lem
      f32x4 sacc[4];
      const uint4 ea = (mt == 0) ? e0 : e2;
      const uint4 eb = (mt == 0) ? e1 : e3;
      sacc[0][0] = bflo(ea.x); sacc[0][1] = bfhi(ea.x);
      sacc[0][2] = bflo(ea.y); sacc[0][3] = bfhi(ea.y);
      sacc[1][0] = bflo(ea.z); sacc[1][1] = bfhi(ea.z);
      sacc[1][2] = bflo(ea.w); sacc[1][3] = bfhi(ea.w);
      sacc[2][0] = bflo(eb.x); sacc[2][1] = bfhi(eb.x);
      sacc[2][2] = bflo(eb.y); sacc[2][3] = bfhi(eb.y);
      sacc[3][0] = bflo(eb.z); sacc[3][1] = bfhi(eb.z);
      sacc[3][2] = bflo(eb.w); sacc[3][3] = bfhi(eb.w);
#pragma unroll
      for (int nt = 0; nt < 4; ++nt)
#pragma unroll
        for (int ks = 0; ks < 2; ++ks)
          sacc[nt] = __builtin_amdgcn_mfma_f32_16x16x32_bf16(bk_[nt][ks], aq[mt][ks],
                                                             sacc[nt], 0, 0, 0);
      // p = exp2(s); pack to in-register PV A-frags: pos = ks*32+g*8+j -> key (2ks+(j>>2))*16+g*4+(j&3)
      float p[4][4];
#pragma unroll
      for (int nt = 0; nt < 4; ++nt)
#pragma unroll
        for (int r = 0; r < 4; ++r) p[nt][r] = __builtin_amdgcn_exp2f(sacc[nt][r]);
      unsigned int wd[8];
#pragma unroll
      for (int ks = 0; ks < 2; ++ks) {
        wd[ks * 4 + 0] = pack2(p[2 * ks][1],     p[2 * ks][0]);
        wd[ks * 4 + 1] = pack2(p[2 * ks][3],     p[2 * ks][2]);
        wd[ks * 4 + 2] = pack2(p[2 * ks + 1][1], p[2 * ks + 1][0]);
        wd[ks * 4 + 3] = pack2(p[2 * ks + 1][3], p[2 * ks + 1][2]);
        u32x4 uv = {wd[ks * 4], wd[ks * 4 + 1], wd[ks * 4 + 2], wd[ks * 4 + 3]};
        ap[mt][ks] = __builtin_bit_cast(bf16x8, uv);
      }
      // li sums the truncated values so numerator/denominator stay consistent
#pragma unroll
      for (int j = 0; j < 8; ++j) li[mt] += bflo(wd[j]) + bfhi(wd[j]);
    }

    // O += P @ V (k-dim = permuted pos, matches Vs column order)
#pragma unroll
    for (int mt = 0; mt < 2; ++mt)
#pragma unroll
      for (int nt = 0; nt < 4; ++nt)
#pragma unroll
        for (int ks = 0; ks < 2; ++ks)
          oacc[mt][nt] = __builtin_amdgcn_mfma_f32_16x16x32_bf16(ap[mt][ks], bv[nt][ks],
                                                                 oacc[mt][nt], 0, 0, 0);
  }

  // epilogue: li per lane covers keys {nt*16+g*4+r} -> reduce over g (xor 16, 32);
  // full li for q = mt*16+cc sits at every lane after the reduce; shfl to the oacc row owner.
#pragma unroll
  for (int mt = 0; mt < 2; ++mt) {
    float s = li[mt];
    s += __shfl_xor(s, 16);
    s += __shfl_xor(s, 32);
#pragma unroll
    for (int r = 0; r < 4; ++r) {
      float sv = __shfl(s, g * 4 + r);   // lane (g*4+r): cc == g*4+r
      float inv = 1.0f / sv;
      int qrow = q0 + w * 32 + mt * 16 + g * 4 + r;
#pragma unroll
      for (int nt = 0; nt < 4; ++nt)
        out[((size_t)b * LL + qrow) * 1024 + h * 64 + nt * 16 + cc] = oacc[mt][nt][r] * inv;
    }
  }
}

extern "C" void kernel_launch(void* const* d_in, const int* in_sizes, int n_in,
                              void* d_out, int out_size, void* d_ws, size_t ws_size,
                              hipStream_t stream) {
  const float* x    = (const float*)d_in[0];
  const float* mask = (const float*)d_in[1];
  const float* Wq   = (const float*)d_in[2];
  const float* bq   = (const float*)d_in[3];
  const float* Wk   = (const float*)d_in[4];
  const float* bk   = (const float*)d_in[5];
  const float* Wv   = (const float*)d_in[6];
  const float* bv   = (const float*)d_in[7];
  float* out = (float*)d_out;
  (void)in_sizes; (void)n_in; (void)out_size; (void)ws_size;

  char* ws = (char*)d_ws;
  // layout: qkv @0 (24 MiB); xb @24 (8 MiB); Wt @32 (6 MiB);
  // lem @24 (16 MiB) overlaps xb/Wt — dead after qkv_gemm (same-stream serialization)
  unsigned short* qkv = (unsigned short*)(ws);
  unsigned short* xb  = (unsigned short*)(ws + (24u << 20));
  unsigned short* Wt  = (unsigned short*)(ws + (32u << 20));
  unsigned short* lem = (unsigned short*)(ws + (24u << 20));

  cvt_x_kernel<<<dim3(4096), dim3(256), 0, stream>>>(x, xb);
  transpose_w_kernel<<<dim3(16, 16, 3), dim3(256), 0, stream>>>(Wq, Wk, Wv, Wt);
  qkv_gemm_kernel<<<dim3(8, 32, 3), dim3(256), 0, stream>>>(xb, Wt, bq, bk, bv, qkv);
  lem_prep_kernel<<<dim3(16, 32, 2), dim3(256), 0, stream>>>(mask, lem);
  flash_kernel<<<dim3(16, 32), dim3(256), 0, stream>>>(qkv, qkv + 4194304, qkv + 8388608,
                                                       lem, out);
}

// Round 4
// 204.953 us; speedup vs baseline: 1.0717x; 1.0153x over previous
//
#include <hip/hip_runtime.h>

// B=2, L=2048, DIM=1024, H=16, HD=64; scale folded into Q: 0.125*log2e; mask: -60*log2e
#define LL 2048
#define NHEADS 16
#define HDIM 64
#define QSCALE 0.18033688011112042f   // 0.125 * log2(e)
#define MASKC1 -86.56170245333780f    // -60 * log2(e)

typedef __attribute__((ext_vector_type(8))) __bf16 bf16x8;
typedef __attribute__((ext_vector_type(4))) float f32x4;
typedef __attribute__((ext_vector_type(4))) unsigned int u32x4;

__device__ __forceinline__ unsigned short f2bf(float f) {
  unsigned int u = __builtin_bit_cast(unsigned int, f);
  u += 0x7fffu + ((u >> 16) & 1u);   // RNE
  return (unsigned short)(u >> 16);
}

__device__ __forceinline__ bf16x8 ld_frag(const unsigned short* p) {
  return *reinterpret_cast<const bf16x8*>(p);
}

__device__ __forceinline__ float bflo(unsigned int u) {
  return __builtin_bit_cast(float, u << 16);
}
__device__ __forceinline__ float bfhi(unsigned int u) {
  return __builtin_bit_cast(float, u & 0xffff0000u);
}
// pack two floats (truncated to bf16) into one u32: low short = lo, high short = hi
__device__ __forceinline__ unsigned int pack2(float hi, float lo) {
  return __builtin_amdgcn_perm(__builtin_bit_cast(unsigned int, hi),
                               __builtin_bit_cast(unsigned int, lo), 0x07060302u);
}

// async global->LDS, 16B per lane; LDS dest = wave-uniform base + lane*16
__device__ __forceinline__ void async_cp16(const unsigned short* g, unsigned short* l) {
  __builtin_amdgcn_global_load_lds(
      (const __attribute__((address_space(1))) unsigned int*)(unsigned long long)(g),
      (__attribute__((address_space(3))) unsigned int*)(unsigned int)(unsigned long long)(l),
      16, 0, 0);
}

// ---------------- prep: fp32 -> bf16 convert of x ----------------
__global__ __launch_bounds__(256) void cvt_x_kernel(const float* __restrict__ x,
                                                    unsigned short* __restrict__ xb) {
  int i = (blockIdx.x * 256 + threadIdx.x) * 4;
  float4 v = *reinterpret_cast<const float4*>(x + i);
  ushort4 o;
  o.x = f2bf(v.x); o.y = f2bf(v.y); o.z = f2bf(v.z); o.w = f2bf(v.w);
  *reinterpret_cast<ushort4*>(xb + i) = o;
}

// ---------------- prep: W [K][N] fp32 -> Wt [N][K] bf16 ----------------
__global__ __launch_bounds__(256) void transpose_w_kernel(const float* __restrict__ Wq,
                                                          const float* __restrict__ Wk,
                                                          const float* __restrict__ Wv,
                                                          unsigned short* __restrict__ WtAll) {
  int z = blockIdx.z;
  const float* W = (z == 0) ? Wq : (z == 1) ? Wk : Wv;
  unsigned short* dst = WtAll + (size_t)z * 1024 * 1024;
  int n0 = blockIdx.x * 64, k0 = blockIdx.y * 64;
  __shared__ float t[64][65];
  int tx = threadIdx.x & 63, ty = threadIdx.x >> 6;
#pragma unroll
  for (int p = 0; p < 16; ++p) {
    int kr = p * 4 + ty;
    t[kr][tx] = W[(size_t)(k0 + kr) * 1024 + n0 + tx];
  }
  __syncthreads();
#pragma unroll
  for (int p = 0; p < 16; ++p) {
    int nr = p * 4 + ty;
    dst[(size_t)(n0 + nr) * 1024 + k0 + tx] = f2bf(t[tx][nr]);
  }
}

// ---------------- prep: lem = bf16(mask*MASKC1), per-flash-thread packed ----------------
// Output layout [b][qb(16)][kt(32)][tid(256)][32 shorts = 64B]; 32 shorts ordered
// idx = mt*16 + nt*4 + r  for value lem[q = qb*128 + w*32 + mt*16 + cc][k = kt*64 + nt*16 + g*4 + r].
// Coalesced float4 reads -> LDS bf16 tile [128][72] -> b64 gather (r-pairs adjacent in k).
__global__ __launch_bounds__(256) void lem_prep_kernel(const float* __restrict__ mask,
                                                       unsigned short* __restrict__ lem) {
  const int qb = blockIdx.x, kt = blockIdx.y, b = blockIdx.z;
  const int tid = threadIdx.x;
  __shared__ unsigned short lds[128 * 72];
  {
    const int r0 = tid >> 4;          // 0..15
    const int c0 = (tid & 15) * 4;    // 0..60
#pragma unroll
    for (int p = 0; p < 8; ++p) {
      int row = p * 16 + r0;
      float4 v = *reinterpret_cast<const float4*>(
          mask + ((size_t)b * LL + qb * 128 + row) * LL + kt * 64 + c0);
      ushort4 o;
      o.x = f2bf(v.x * MASKC1); o.y = f2bf(v.y * MASKC1);
      o.z = f2bf(v.z * MASKC1); o.w = f2bf(v.w * MASKC1);
      *reinterpret_cast<ushort4*>(&lds[row * 72 + c0]) = o;
    }
  }
  __syncthreads();
  const int w = tid >> 6, lane = tid & 63, g = lane >> 4, cc = lane & 15;
  unsigned int ow[16];
#pragma unroll
  for (int mt = 0; mt < 2; ++mt) {
    const int q = w * 32 + mt * 16 + cc;
#pragma unroll
    for (int nt = 0; nt < 4; ++nt) {
      uint2 v = *reinterpret_cast<const uint2*>(&lds[q * 72 + nt * 16 + g * 4]);
      ow[mt * 8 + nt * 2]     = v.x;   // r0 (lo), r1 (hi)
      ow[mt * 8 + nt * 2 + 1] = v.y;   // r2 (lo), r3 (hi)
    }
  }
  uint4* dst = reinterpret_cast<uint4*>(
      lem + ((((size_t)b * 16 + qb) * 32 + kt) * 256 + tid) * 32);
#pragma unroll
  for (int j = 0; j < 4; ++j)
    dst[j] = make_uint4(ow[4 * j], ow[4 * j + 1], ow[4 * j + 2], ow[4 * j + 3]);
}

// ---------------- QKV projection GEMM (m97-style async staging, swizzled rows) ----------------
// grid (8, 32, 3). z==0: Q bf16 [bh][l][d] * QSCALE; z==1: K; z==2: V^T [bh][d][pos], key-permuted
// with pos(key6) = (key6>>5)*32 + ((key6>>2)&3)*8 + ((key6>>4)&1)*4 + (key6&3).
__global__ __launch_bounds__(256) void qkv_gemm_kernel(
    const unsigned short* __restrict__ xb, const unsigned short* __restrict__ WtAll,
    const float* __restrict__ bq, const float* __restrict__ bk, const float* __restrict__ bv,
    unsigned short* __restrict__ qkv) {
  const int z = blockIdx.z;
  const unsigned short* Wt = WtAll + (size_t)z * 1024 * 1024;
  const float* bias = (z == 0) ? bq : (z == 1) ? bk : bv;
  unsigned short* outb = qkv + (size_t)z * 4194304;

  __shared__ __align__(16) unsigned short smem[16384];  // As 8192, Bs 8192 (stride 64, swizzled)
  unsigned short* As = smem;
  unsigned short* Bs = smem + 8192;

  const int tid = threadIdx.x;
  const int w = tid >> 6, lane = tid & 63, g = lane >> 4, cc = lane & 15;
  const int wm = w >> 1, wn = w & 1;
  const int m0 = blockIdx.y * 128, n0 = blockIdx.x * 128;
  const int srow = lane >> 3;                 // row within seg
  const int gc = ((lane & 7) - srow) & 7;     // swizzle: LDS slot s holds chunk (s - row)&7
  const unsigned short* ga = xb + (size_t)(m0 + w * 32 + srow) * 1024 + gc * 8;
  const unsigned short* gb = Wt + (size_t)(n0 + w * 32 + srow) * 1024 + gc * 8;
  unsigned short* la = As + w * 2048;   // 4 segs * 512
  unsigned short* lb = Bs + w * 2048;

  f32x4 acc[4][4];
#pragma unroll
  for (int i = 0; i < 4; ++i)
#pragma unroll
    for (int j = 0; j < 4; ++j) acc[i][j] = (f32x4)0.0f;

  for (int kk = 0; kk < 1024; kk += 64) {
    __syncthreads();
#pragma unroll
    for (int i = 0; i < 4; ++i) {
      async_cp16(ga + i * 8192 + kk, la + i * 512);
      async_cp16(gb + i * 8192 + kk, lb + i * 512);
    }
    __syncthreads();  // compiler emits vmcnt(0) drain before barrier
    bf16x8 af[4][2], bfr[4][2];
#pragma unroll
    for (int mt = 0; mt < 4; ++mt)
#pragma unroll
      for (int ks = 0; ks < 2; ++ks)
        af[mt][ks] = ld_frag(&As[(wm * 64 + mt * 16 + cc) * 64 + ((4 * ks + g + cc) & 7) * 8]);
#pragma unroll
    for (int nt = 0; nt < 4; ++nt)
#pragma unroll
      for (int ks = 0; ks < 2; ++ks)
        bfr[nt][ks] = ld_frag(&Bs[(wn * 64 + nt * 16 + cc) * 64 + ((4 * ks + g + cc) & 7) * 8]);
#pragma unroll
    for (int mt = 0; mt < 4; ++mt)
#pragma unroll
      for (int nt = 0; nt < 4; ++nt)
#pragma unroll
        for (int ks = 0; ks < 2; ++ks)
          acc[mt][nt] = __builtin_amdgcn_mfma_f32_16x16x32_bf16(af[mt][ks], bfr[nt][ks],
                                                                acc[mt][nt], 0, 0, 0);
  }

  if (z != 2) {
    const float sc = (z == 0) ? QSCALE : 1.0f;
#pragma unroll
    for (int nt = 0; nt < 4; ++nt) {
      int n = n0 + wn * 64 + nt * 16 + cc;
      float bval = bias[n];
      int h = n >> 6, d = n & 63;
#pragma unroll
      for (int mt = 0; mt < 4; ++mt) {
#pragma unroll
        for (int r = 0; r < 4; ++r) {
          int m = m0 + wm * 64 + mt * 16 + g * 4 + r;
          int b = m >> 11, l = m & 2047;
          outb[(((size_t)(b * NHEADS + h) * LL) + l) * HDIM + d] =
              f2bf((acc[mt][nt][r] + bval) * sc);
        }
      }
    }
  } else {
    // V^T epilogue with key permutation: key6 = mt*16 + g*4 + r
    // -> pos = (mt>>1)*32 + g*8 + (mt&1)*4 + r   (inverse of flash's in-register P layout)
    __syncthreads();
#pragma unroll
    for (int nt = 0; nt < 4; ++nt) {
      int nr = wn * 64 + nt * 16 + cc;
      float bval = bias[n0 + nr];
#pragma unroll
      for (int mt = 0; mt < 4; ++mt)
#pragma unroll
        for (int r = 0; r < 4; ++r)
          smem[nr * 128 + wm * 64 + (mt >> 1) * 32 + g * 8 + (mt & 1) * 4 + r] =
              f2bf(acc[mt][nt][r] + bval);
    }
    __syncthreads();
    int row = tid >> 1, half = tid & 1;
    int n = n0 + row, hh = n >> 6, dd = n & 63;
    int bb = m0 >> 11, l0 = (m0 & 2047) + half * 64;
    unsigned short* dst = outb + ((size_t)(bb * NHEADS + hh) * HDIM + dd) * LL + l0;
#pragma unroll
    for (int i = 0; i < 8; ++i)
      *reinterpret_cast<uint4*>(dst + i * 8) =
          *reinterpret_cast<const uint4*>(&smem[row * 128 + half * 64 + i * 8]);
  }
}

// ---------------- flash attention ----------------
// grid (16, 32): q-tile 128, 4 waves x 32 q-rows, 2 blocks/CU. Swapped QK^T (S^T = K*Q^T)
// puts P lane-local (q = cc) -> P packs straight into in-register PV A-frags via the
// key-permuted V^T; no P LDS buffer. lem folded into MFMA C-init, REG-PREFETCHED one kt
// ahead (next barrier's vmcnt(0) drain guarantees completion -> zero exposed latency).
// li computed by MFMA against an all-ones B-frag (sums the same truncated bf16 P values;
// lands in oacc's row layout -> no epilogue shuffles).
__global__ __launch_bounds__(256, 2) void flash_kernel(
    const unsigned short* __restrict__ Qb, const unsigned short* __restrict__ Kb,
    const unsigned short* __restrict__ Vt, const unsigned short* __restrict__ Lem,
    float* __restrict__ out) {
  const int id = blockIdx.y * 16 + blockIdx.x;   // 512 blocks
  const int nid = (id & 7) * 64 + (id >> 3);     // bijective XCD swizzle (512 % 8 == 0)
  const int qb = nid & 15, bh = nid >> 4;
  const int b = bh >> 4, h = bh & 15;
  const int q0 = qb * 128;
  const int tid = threadIdx.x, w = tid >> 6, lane = tid & 63, g = lane >> 4, cc = lane & 15;
  const size_t bhoff = (size_t)bh * LL * HDIM;

  __shared__ __align__(16) unsigned short Ks[2][64 * 64];  // [key][d], swizzled chunks
  __shared__ __align__(16) unsigned short Vs[2][64 * 64];  // [d][pos], swizzled chunks

  // Q fragments (B operand of swapped QK^T): lane (g,cc) holds Q[q0+w*32+mt*16+cc][ks*32+g*8..]
  bf16x8 aq[2][2];
#pragma unroll
  for (int mt = 0; mt < 2; ++mt)
#pragma unroll
    for (int ks = 0; ks < 2; ++ks)
      aq[mt][ks] = *reinterpret_cast<const bf16x8*>(
          Qb + bhoff + (size_t)(q0 + w * 32 + mt * 16 + cc) * HDIM + ks * 32 + g * 8);

  // async staging: wave w stages K segs {w, w+4} and V segs {w, w+4}
  const int srow = lane >> 3;
  const int gcs = ((lane & 7) - srow) & 7;
  const unsigned short* kg0 = Kb + bhoff + (size_t)(w * 8 + srow) * HDIM + gcs * 8;
  const unsigned short* kg1 = Kb + bhoff + (size_t)(32 + w * 8 + srow) * HDIM + gcs * 8;
  const unsigned short* vg0 = Vt + bhoff + (size_t)(w * 8 + srow) * LL + gcs * 8;
  const unsigned short* vg1 = Vt + bhoff + (size_t)(32 + w * 8 + srow) * LL + gcs * 8;

  // per-thread lem stream: 64B per kt, contiguous
  const uint4* lemp = reinterpret_cast<const uint4*>(
      Lem + (((size_t)b * 16 + qb) * 32 * 256 + tid) * 32);

  // all-ones bf16 B-frag for the li row-sum MFMA
  const u32x4 onesu = {0x3F803F80u, 0x3F803F80u, 0x3F803F80u, 0x3F803F80u};
  const bf16x8 bones = __builtin_bit_cast(bf16x8, onesu);

  f32x4 liacc[2];
  f32x4 oacc[2][4];
#pragma unroll
  for (int mt = 0; mt < 2; ++mt) {
    liacc[mt] = (f32x4)0.0f;
#pragma unroll
    for (int nt = 0; nt < 4; ++nt) oacc[mt][nt] = (f32x4)0.0f;
  }

  // stage tile 0 into buf 0; prefetch lem for kt=0 into regs
  async_cp16(kg0, Ks[0] + w * 512);
  async_cp16(kg1, Ks[0] + (w + 4) * 512);
  async_cp16(vg0, Vs[0] + w * 512);
  async_cp16(vg1, Vs[0] + (w + 4) * 512);
  uint4 e0 = lemp[0], e1 = lemp[1], e2 = lemp[2], e3 = lemp[3];
  lemp += 1024;  // 16 KB per kt

  for (int kt = 0; kt < 32; ++kt) {
    const int buf = kt & 1;
    __syncthreads();  // vmcnt(0) drain: tile kt + lem[kt] regs ready; prior buf^1 reads done
    uint4 f0 = e0, f1 = e1, f2 = e2, f3 = e3;
    if (kt + 1 < 32) {
      const int nb = buf ^ 1;
      async_cp16(kg0 + (size_t)(kt + 1) * 64 * HDIM, Ks[nb] + w * 512);
      async_cp16(kg1 + (size_t)(kt + 1) * 64 * HDIM, Ks[nb] + (w + 4) * 512);
      async_cp16(vg0 + (kt + 1) * 64, Vs[nb] + w * 512);
      async_cp16(vg1 + (kt + 1) * 64, Vs[nb] + (w + 4) * 512);
      // prefetch lem for kt+1; consumed only after the next barrier's drain
      f0 = lemp[0]; f1 = lemp[1]; f2 = lemp[2]; f3 = lemp[3];
      lemp += 1024;
    }

    // K fragments (A operand): lane (cc,g) holds K[nt*16+cc][ks*32+g*8..]; shared by both mt
    bf16x8 bk_[4][2];
#pragma unroll
    for (int nt = 0; nt < 4; ++nt)
#pragma unroll
      for (int ks = 0; ks < 2; ++ks)
        bk_[nt][ks] =
            ld_frag(&Ks[buf][(nt * 16 + cc) * 64 + ((4 * ks + g + cc) & 7) * 8]);
    // V fragments (B operand of PV), issued early to keep the LDS pipe busy under softmax
    bf16x8 bv[4][2];
#pragma unroll
    for (int nt = 0; nt < 4; ++nt)
#pragma unroll
      for (int ks = 0; ks < 2; ++ks)
        bv[nt][ks] =
            ld_frag(&Vs[buf][(nt * 16 + cc) * 64 + ((4 * ks + g + cc) & 7) * 8]);

    bf16x8 ap[2][2];
#pragma unroll
    for (int mt = 0; mt < 2; ++mt) {
      // S^T tile: sacc[nt] lane (cc,g) = S[key nt*16+g*4+r][q = w*32+mt*16+cc], C-init = lem
      f32x4 sacc[4];
      const uint4 ea = (mt == 0) ? e0 : e2;
      const uint4 eb = (mt == 0) ? e1 : e3;
      sacc[0][0] = bflo(ea.x); sacc[0][1] = bfhi(ea.x);
      sacc[0][2] = bflo(ea.y); sacc[0][3] = bfhi(ea.y);
      sacc[1][0] = bflo(ea.z); sacc[1][1] = bfhi(ea.z);
      sacc[1][2] = bflo(ea.w); sacc[1][3] = bfhi(ea.w);
      sacc[2][0] = bflo(eb.x); sacc[2][1] = bfhi(eb.x);
      sacc[2][2] = bflo(eb.y); sacc[2][3] = bfhi(eb.y);
      sacc[3][0] = bflo(eb.z); sacc[3][1] = bfhi(eb.z);
      sacc[3][2] = bflo(eb.w); sacc[3][3] = bfhi(eb.w);
#pragma unroll
      for (int nt = 0; nt < 4; ++nt)
#pragma unroll
        for (int ks = 0; ks < 2; ++ks)
          sacc[nt] = __builtin_amdgcn_mfma_f32_16x16x32_bf16(bk_[nt][ks], aq[mt][ks],
                                                             sacc[nt], 0, 0, 0);
      // p = exp2(s); pack to in-register PV A-frags: pos = ks*32+g*8+j -> key (2ks+(j>>2))*16+g*4+(j&3)
      float p[4][4];
#pragma unroll
      for (int nt = 0; nt < 4; ++nt)
#pragma unroll
        for (int r = 0; r < 4; ++r) p[nt][r] = __builtin_amdgcn_exp2f(sacc[nt][r]);
      unsigned int wd[8];
#pragma unroll
      for (int ks = 0; ks < 2; ++ks) {
        wd[ks * 4 + 0] = pack2(p[2 * ks][1],     p[2 * ks][0]);
        wd[ks * 4 + 1] = pack2(p[2 * ks][3],     p[2 * ks][2]);
        wd[ks * 4 + 2] = pack2(p[2 * ks + 1][1], p[2 * ks + 1][0]);
        wd[ks * 4 + 3] = pack2(p[2 * ks + 1][3], p[2 * ks + 1][2]);
        u32x4 uv = {wd[ks * 4], wd[ks * 4 + 1], wd[ks * 4 + 2], wd[ks * 4 + 3]};
        ap[mt][ks] = __builtin_bit_cast(bf16x8, uv);
      }
    }

    // O += P @ V (k-dim = permuted pos, matches Vs column order);
    // li += P @ ones (same truncated bf16 values -> numer/denom stay consistent)
#pragma unroll
    for (int mt = 0; mt < 2; ++mt) {
#pragma unroll
      for (int nt = 0; nt < 4; ++nt)
#pragma unroll
        for (int ks = 0; ks < 2; ++ks)
          oacc[mt][nt] = __builtin_amdgcn_mfma_f32_16x16x32_bf16(ap[mt][ks], bv[nt][ks],
                                                                 oacc[mt][nt], 0, 0, 0);
#pragma unroll
      for (int ks = 0; ks < 2; ++ks)
        liacc[mt] = __builtin_amdgcn_mfma_f32_16x16x32_bf16(ap[mt][ks], bones,
                                                            liacc[mt], 0, 0, 0);
    }

    e0 = f0; e1 = f1; e2 = f2; e3 = f3;
  }

  // epilogue: liacc[mt][r] = sum_k P for q = w*32+mt*16+g*4+r (same row layout as oacc)
#pragma unroll
  for (int mt = 0; mt < 2; ++mt) {
#pragma unroll
    for (int r = 0; r < 4; ++r) {
      float inv = 1.0f / liacc[mt][r];
      int qrow = q0 + w * 32 + mt * 16 + g * 4 + r;
#pragma unroll
      for (int nt = 0; nt < 4; ++nt)
        out[((size_t)b * LL + qrow) * 1024 + h * 64 + nt * 16 + cc] = oacc[mt][nt][r] * inv;
    }
  }
}

extern "C" void kernel_launch(void* const* d_in, const int* in_sizes, int n_in,
                              void* d_out, int out_size, void* d_ws, size_t ws_size,
                              hipStream_t stream) {
  const float* x    = (const float*)d_in[0];
  const float* mask = (const float*)d_in[1];
  const float* Wq   = (const float*)d_in[2];
  const float* bq   = (const float*)d_in[3];
  const float* Wk   = (const float*)d_in[4];
  const float* bk   = (const float*)d_in[5];
  const float* Wv   = (const float*)d_in[6];
  const float* bv   = (const float*)d_in[7];
  float* out = (float*)d_out;
  (void)in_sizes; (void)n_in; (void)out_size; (void)ws_size;

  char* ws = (char*)d_ws;
  // layout: qkv @0 (24 MiB); xb @24 (8 MiB); Wt @32 (6 MiB);
  // lem @24 (16 MiB) overlaps xb/Wt — dead after qkv_gemm (same-stream serialization)
  unsigned short* qkv = (unsigned short*)(ws);
  unsigned short* xb  = (unsigned short*)(ws + (24u << 20));
  unsigned short* Wt  = (unsigned short*)(ws + (32u << 20));
  unsigned short* lem = (unsigned short*)(ws + (24u << 20));

  cvt_x_kernel<<<dim3(4096), dim3(256), 0, stream>>>(x, xb);
  transpose_w_kernel<<<dim3(16, 16, 3), dim3(256), 0, stream>>>(Wq, Wk, Wv, Wt);
  qkv_gemm_kernel<<<dim3(8, 32, 3), dim3(256), 0, stream>>>(xb, Wt, bq, bk, bv, qkv);
  lem_prep_kernel<<<dim3(16, 32, 2), dim3(256), 0, stream>>>(mask, lem);
  flash_kernel<<<dim3(16, 32), dim3(256), 0, stream>>>(qkv, qkv + 4194304, qkv + 8388608,
                                                       lem, out);
}

// Round 5
// 201.199 us; speedup vs baseline: 1.0917x; 1.0187x over previous
//
#include <hip/hip_runtime.h>

// B=2, L=2048, DIM=1024, H=16, HD=64; scale folded into Q: 0.125*log2e; mask: -60*log2e
#define LL 2048
#define NHEADS 16
#define HDIM 64
#define QSCALE 0.18033688011112042f   // 0.125 * log2(e)
#define MASKC1 -86.56170245333780f    // -60 * log2(e)

typedef __attribute__((ext_vector_type(8))) __bf16 bf16x8;
typedef __attribute__((ext_vector_type(4))) float f32x4;
typedef __attribute__((ext_vector_type(4))) unsigned int u32x4;

__device__ __forceinline__ unsigned short f2bf(float f) {
  unsigned int u = __builtin_bit_cast(unsigned int, f);
  u += 0x7fffu + ((u >> 16) & 1u);   // RNE
  return (unsigned short)(u >> 16);
}

__device__ __forceinline__ bf16x8 ld_frag(const unsigned short* p) {
  return *reinterpret_cast<const bf16x8*>(p);
}

__device__ __forceinline__ float bflo(unsigned int u) {
  return __builtin_bit_cast(float, u << 16);
}
__device__ __forceinline__ float bfhi(unsigned int u) {
  return __builtin_bit_cast(float, u & 0xffff0000u);
}
// pack two floats (truncated to bf16) into one u32: low short = lo, high short = hi
__device__ __forceinline__ unsigned int pack2(float hi, float lo) {
  return __builtin_amdgcn_perm(__builtin_bit_cast(unsigned int, hi),
                               __builtin_bit_cast(unsigned int, lo), 0x07060302u);
}

// async global->LDS, 16B per lane; LDS dest = wave-uniform base + lane*16
__device__ __forceinline__ void async_cp16(const unsigned short* g, unsigned short* l) {
  __builtin_amdgcn_global_load_lds(
      (const __attribute__((address_space(1))) unsigned int*)(unsigned long long)(g),
      (__attribute__((address_space(3))) unsigned int*)(unsigned int)(unsigned long long)(l),
      16, 0, 0);
}

// 64B lem prefetch via inline asm (keeps compiler's waitcnt bookkeeping out of the
// pipeline; completion is guaranteed by the manual counted vmcnt at ITER top).
// "=&v" early-clobber: dests must not alias the address pair (async completion).
__device__ __forceinline__ void lem_load(const unsigned short* p, uint4& a, uint4& b,
                                         uint4& c, uint4& d) {
  asm volatile("global_load_dwordx4 %0, %4, off\n\t"
               "global_load_dwordx4 %1, %4, off offset:16\n\t"
               "global_load_dwordx4 %2, %4, off offset:32\n\t"
               "global_load_dwordx4 %3, %4, off offset:48"
               : "=&v"(a), "=&v"(b), "=&v"(c), "=&v"(d)
               : "v"(p)
               : "memory");
}

// ---------------- prep: fp32 -> bf16 convert of x ----------------
__global__ __launch_bounds__(256) void cvt_x_kernel(const float* __restrict__ x,
                                                    unsigned short* __restrict__ xb) {
  int i = (blockIdx.x * 256 + threadIdx.x) * 4;
  float4 v = *reinterpret_cast<const float4*>(x + i);
  ushort4 o;
  o.x = f2bf(v.x); o.y = f2bf(v.y); o.z = f2bf(v.z); o.w = f2bf(v.w);
  *reinterpret_cast<ushort4*>(xb + i) = o;
}

// ---------------- prep: W [K][N] fp32 -> Wt [N][K] bf16 ----------------
__global__ __launch_bounds__(256) void transpose_w_kernel(const float* __restrict__ Wq,
                                                          const float* __restrict__ Wk,
                                                          const float* __restrict__ Wv,
                                                          unsigned short* __restrict__ WtAll) {
  int z = blockIdx.z;
  const float* W = (z == 0) ? Wq : (z == 1) ? Wk : Wv;
  unsigned short* dst = WtAll + (size_t)z * 1024 * 1024;
  int n0 = blockIdx.x * 64, k0 = blockIdx.y * 64;
  __shared__ float t[64][65];
  int tx = threadIdx.x & 63, ty = threadIdx.x >> 6;
#pragma unroll
  for (int p = 0; p < 16; ++p) {
    int kr = p * 4 + ty;
    t[kr][tx] = W[(size_t)(k0 + kr) * 1024 + n0 + tx];
  }
  __syncthreads();
#pragma unroll
  for (int p = 0; p < 16; ++p) {
    int nr = p * 4 + ty;
    dst[(size_t)(n0 + nr) * 1024 + k0 + tx] = f2bf(t[tx][nr]);
  }
}

// ---------------- prep: lem = bf16(mask*MASKC1), per-flash-thread packed ----------------
// Output layout [b][qb(16)][kt(32)][tid(256)][32 shorts = 64B]; 32 shorts ordered
// idx = mt*16 + nt*4 + r  for value lem[q = qb*128 + w*32 + mt*16 + cc][k = kt*64 + nt*16 + g*4 + r].
// Coalesced float4 reads -> LDS bf16 tile [128][72] -> b64 gather (r-pairs adjacent in k).
__global__ __launch_bounds__(256) void lem_prep_kernel(const float* __restrict__ mask,
                                                       unsigned short* __restrict__ lem) {
  const int qb = blockIdx.x, kt = blockIdx.y, b = blockIdx.z;
  const int tid = threadIdx.x;
  __shared__ unsigned short lds[128 * 72];
  {
    const int r0 = tid >> 4;          // 0..15
    const int c0 = (tid & 15) * 4;    // 0..60
#pragma unroll
    for (int p = 0; p < 8; ++p) {
      int row = p * 16 + r0;
      float4 v = *reinterpret_cast<const float4*>(
          mask + ((size_t)b * LL + qb * 128 + row) * LL + kt * 64 + c0);
      ushort4 o;
      o.x = f2bf(v.x * MASKC1); o.y = f2bf(v.y * MASKC1);
      o.z = f2bf(v.z * MASKC1); o.w = f2bf(v.w * MASKC1);
      *reinterpret_cast<ushort4*>(&lds[row * 72 + c0]) = o;
    }
  }
  __syncthreads();
  const int w = tid >> 6, lane = tid & 63, g = lane >> 4, cc = lane & 15;
  unsigned int ow[16];
#pragma unroll
  for (int mt = 0; mt < 2; ++mt) {
    const int q = w * 32 + mt * 16 + cc;
#pragma unroll
    for (int nt = 0; nt < 4; ++nt) {
      uint2 v = *reinterpret_cast<const uint2*>(&lds[q * 72 + nt * 16 + g * 4]);
      ow[mt * 8 + nt * 2]     = v.x;   // r0 (lo), r1 (hi)
      ow[mt * 8 + nt * 2 + 1] = v.y;   // r2 (lo), r3 (hi)
    }
  }
  uint4* dst = reinterpret_cast<uint4*>(
      lem + ((((size_t)b * 16 + qb) * 32 + kt) * 256 + tid) * 32);
#pragma unroll
  for (int j = 0; j < 4; ++j)
    dst[j] = make_uint4(ow[4 * j], ow[4 * j + 1], ow[4 * j + 2], ow[4 * j + 3]);
}

// ---------------- QKV projection GEMM (m97-style async staging, swizzled rows) ----------------
// grid (8, 32, 3). z==0: Q bf16 [bh][l][d] * QSCALE; z==1: K; z==2: V^T [bh][d][pos], key-permuted
// with pos(key6) = (key6>>5)*32 + ((key6>>2)&3)*8 + ((key6>>4)&1)*4 + (key6&3).
__global__ __launch_bounds__(256) void qkv_gemm_kernel(
    const unsigned short* __restrict__ xb, const unsigned short* __restrict__ WtAll,
    const float* __restrict__ bq, const float* __restrict__ bk, const float* __restrict__ bv,
    unsigned short* __restrict__ qkv) {
  const int z = blockIdx.z;
  const unsigned short* Wt = WtAll + (size_t)z * 1024 * 1024;
  const float* bias = (z == 0) ? bq : (z == 1) ? bk : bv;
  unsigned short* outb = qkv + (size_t)z * 4194304;

  __shared__ __align__(16) unsigned short smem[16384];  // As 8192, Bs 8192 (stride 64, swizzled)
  unsigned short* As = smem;
  unsigned short* Bs = smem + 8192;

  const int tid = threadIdx.x;
  const int w = tid >> 6, lane = tid & 63, g = lane >> 4, cc = lane & 15;
  const int wm = w >> 1, wn = w & 1;
  const int m0 = blockIdx.y * 128, n0 = blockIdx.x * 128;
  const int srow = lane >> 3;                 // row within seg
  const int gc = ((lane & 7) - srow) & 7;     // swizzle: LDS slot s holds chunk (s - row)&7
  const unsigned short* ga = xb + (size_t)(m0 + w * 32 + srow) * 1024 + gc * 8;
  const unsigned short* gb = Wt + (size_t)(n0 + w * 32 + srow) * 1024 + gc * 8;
  unsigned short* la = As + w * 2048;   // 4 segs * 512
  unsigned short* lb = Bs + w * 2048;

  f32x4 acc[4][4];
#pragma unroll
  for (int i = 0; i < 4; ++i)
#pragma unroll
    for (int j = 0; j < 4; ++j) acc[i][j] = (f32x4)0.0f;

  for (int kk = 0; kk < 1024; kk += 64) {
    __syncthreads();
#pragma unroll
    for (int i = 0; i < 4; ++i) {
      async_cp16(ga + i * 8192 + kk, la + i * 512);
      async_cp16(gb + i * 8192 + kk, lb + i * 512);
    }
    __syncthreads();  // compiler emits vmcnt(0) drain before barrier
    bf16x8 af[4][2], bfr[4][2];
#pragma unroll
    for (int mt = 0; mt < 4; ++mt)
#pragma unroll
      for (int ks = 0; ks < 2; ++ks)
        af[mt][ks] = ld_frag(&As[(wm * 64 + mt * 16 + cc) * 64 + ((4 * ks + g + cc) & 7) * 8]);
#pragma unroll
    for (int nt = 0; nt < 4; ++nt)
#pragma unroll
      for (int ks = 0; ks < 2; ++ks)
        bfr[nt][ks] = ld_frag(&Bs[(wn * 64 + nt * 16 + cc) * 64 + ((4 * ks + g + cc) & 7) * 8]);
#pragma unroll
    for (int mt = 0; mt < 4; ++mt)
#pragma unroll
      for (int nt = 0; nt < 4; ++nt)
#pragma unroll
        for (int ks = 0; ks < 2; ++ks)
          acc[mt][nt] = __builtin_amdgcn_mfma_f32_16x16x32_bf16(af[mt][ks], bfr[nt][ks],
                                                                acc[mt][nt], 0, 0, 0);
  }

  if (z != 2) {
    const float sc = (z == 0) ? QSCALE : 1.0f;
#pragma unroll
    for (int nt = 0; nt < 4; ++nt) {
      int n = n0 + wn * 64 + nt * 16 + cc;
      float bval = bias[n];
      int h = n >> 6, d = n & 63;
#pragma unroll
      for (int mt = 0; mt < 4; ++mt) {
#pragma unroll
        for (int r = 0; r < 4; ++r) {
          int m = m0 + wm * 64 + mt * 16 + g * 4 + r;
          int b = m >> 11, l = m & 2047;
          outb[(((size_t)(b * NHEADS + h) * LL) + l) * HDIM + d] =
              f2bf((acc[mt][nt][r] + bval) * sc);
        }
      }
    }
  } else {
    // V^T epilogue with key permutation: key6 = mt*16 + g*4 + r
    // -> pos = (mt>>1)*32 + g*8 + (mt&1)*4 + r   (inverse of flash's in-register P layout)
    __syncthreads();
#pragma unroll
    for (int nt = 0; nt < 4; ++nt) {
      int nr = wn * 64 + nt * 16 + cc;
      float bval = bias[n0 + nr];
#pragma unroll
      for (int mt = 0; mt < 4; ++mt)
#pragma unroll
        for (int r = 0; r < 4; ++r)
          smem[nr * 128 + wm * 64 + (mt >> 1) * 32 + g * 8 + (mt & 1) * 4 + r] =
              f2bf(acc[mt][nt][r] + bval);
    }
    __syncthreads();
    int row = tid >> 1, half = tid & 1;
    int n = n0 + row, hh = n >> 6, dd = n & 63;
    int bb = m0 >> 11, l0 = (m0 & 2047) + half * 64;
    unsigned short* dst = outb + ((size_t)(bb * NHEADS + hh) * HDIM + dd) * LL + l0;
#pragma unroll
    for (int i = 0; i < 8; ++i)
      *reinterpret_cast<uint4*>(dst + i * 8) =
          *reinterpret_cast<const uint4*>(&smem[row * 128 + half * 64 + i * 8]);
  }
}

// ---------------- flash attention ----------------
// grid (16, 32): q-tile 128, 4 waves x 32 q-rows, 2 blocks/CU. Swapped QK^T; P packed
// in-register into PV A-frags (key-permuted V^T); lem folded into MFMA C-init.
// T3/T4 schedule: 3 LDS buffers, stage(kt+2) each iter (4 cp16 + 4 asm lem = 8 VMEM),
// raw s_barrier with COUNTED s_waitcnt vmcnt(8) -> tile kt+1 stays in flight across
// the barrier (2 compute-iters of latency cover). li via ones-MFMA.
__global__ __launch_bounds__(256, 2) void flash_kernel(
    const unsigned short* __restrict__ Qb, const unsigned short* __restrict__ Kb,
    const unsigned short* __restrict__ Vt, const unsigned short* __restrict__ Lem,
    float* __restrict__ out) {
  const int id = blockIdx.y * 16 + blockIdx.x;   // 512 blocks
  const int nid = (id & 7) * 64 + (id >> 3);     // bijective XCD swizzle (512 % 8 == 0)
  const int qb = nid & 15, bh = nid >> 4;
  const int b = bh >> 4, h = bh & 15;
  const int q0 = qb * 128;
  const int tid = threadIdx.x, w = tid >> 6, lane = tid & 63, g = lane >> 4, cc = lane & 15;
  const size_t bhoff = (size_t)bh * LL * HDIM;

  __shared__ __align__(16) unsigned short Ks[3][64 * 64];  // [key][d], swizzled chunks
  __shared__ __align__(16) unsigned short Vs[3][64 * 64];  // [d][pos], swizzled chunks

  // Q fragments (B operand of swapped QK^T): lane (g,cc) holds Q[q0+w*32+mt*16+cc][ks*32+g*8..]
  bf16x8 aq[2][2];
#pragma unroll
  for (int mt = 0; mt < 2; ++mt)
#pragma unroll
    for (int ks = 0; ks < 2; ++ks)
      aq[mt][ks] = *reinterpret_cast<const bf16x8*>(
          Qb + bhoff + (size_t)(q0 + w * 32 + mt * 16 + cc) * HDIM + ks * 32 + g * 8);

  // async staging: wave w stages K segs {w, w+4} and V segs {w, w+4}
  const int srow = lane >> 3;
  const int gcs = ((lane & 7) - srow) & 7;
  const unsigned short* kg0 = Kb + bhoff + (size_t)(w * 8 + srow) * HDIM + gcs * 8;
  const unsigned short* kg1 = Kb + bhoff + (size_t)(32 + w * 8 + srow) * HDIM + gcs * 8;
  const unsigned short* vg0 = Vt + bhoff + (size_t)(w * 8 + srow) * LL + gcs * 8;
  const unsigned short* vg1 = Vt + bhoff + (size_t)(32 + w * 8 + srow) * LL + gcs * 8;

  // per-thread lem stream: 64B per kt, contiguous
  const unsigned short* lemq = Lem + (((size_t)b * 16 + qb) * 32 * 256 + tid) * 32;

  // all-ones bf16 B-frag for the li row-sum MFMA
  const u32x4 onesu = {0x3F803F80u, 0x3F803F80u, 0x3F803F80u, 0x3F803F80u};
  const bf16x8 bones = __builtin_bit_cast(bf16x8, onesu);

  // 3 rotating lem register sets (4 uint4 each)
  uint4 l00, l01, l02, l03, l10, l11, l12, l13, l20, l21, l22, l23;

  f32x4 liacc[2];
  f32x4 oacc[2][4];
#pragma unroll
  for (int mt = 0; mt < 2; ++mt) {
    liacc[mt] = (f32x4)0.0f;
#pragma unroll
    for (int nt = 0; nt < 4; ++nt) oacc[mt][nt] = (f32x4)0.0f;
  }

  // prologue: stage KV(0)->buf0 + lem(0)->set0; KV(1)->buf1 + lem(1)->set1
  async_cp16(kg0, Ks[0] + w * 512);
  async_cp16(kg1, Ks[0] + (w + 4) * 512);
  async_cp16(vg0, Vs[0] + w * 512);
  async_cp16(vg1, Vs[0] + (w + 4) * 512);
  lem_load(lemq, l00, l01, l02, l03);
  lemq += 8192;
  async_cp16(kg0 + (size_t)64 * HDIM, Ks[1] + w * 512);
  async_cp16(kg1 + (size_t)64 * HDIM, Ks[1] + (w + 4) * 512);
  async_cp16(vg0 + 64, Vs[1] + w * 512);
  async_cp16(vg1 + 64, Vs[1] + (w + 4) * 512);
  lem_load(lemq, l10, l11, l12, l13);
  lemq += 8192;

#define FLASH_COMPUTE(BUF, LSA, LSB, LSC, LSD)                                         \
  {                                                                                    \
    bf16x8 bk_[4][2], bv[4][2];                                                        \
    _Pragma("unroll") for (int nt = 0; nt < 4; ++nt)                                   \
      _Pragma("unroll") for (int ks = 0; ks < 2; ++ks)                                 \
        bk_[nt][ks] =                                                                  \
            ld_frag(&Ks[BUF][(nt * 16 + cc) * 64 + ((4 * ks + g + cc) & 7) * 8]);      \
    _Pragma("unroll") for (int nt = 0; nt < 4; ++nt)                                   \
      _Pragma("unroll") for (int ks = 0; ks < 2; ++ks)                                 \
        bv[nt][ks] =                                                                   \
            ld_frag(&Vs[BUF][(nt * 16 + cc) * 64 + ((4 * ks + g + cc) & 7) * 8]);      \
    bf16x8 ap[2][2];                                                                   \
    _Pragma("unroll") for (int mt = 0; mt < 2; ++mt) {                                 \
      f32x4 sacc[4];                                                                   \
      const uint4 ea = (mt == 0) ? LSA : LSC;                                          \
      const uint4 eb = (mt == 0) ? LSB : LSD;                                          \
      sacc[0][0] = bflo(ea.x); sacc[0][1] = bfhi(ea.x);                                \
      sacc[0][2] = bflo(ea.y); sacc[0][3] = bfhi(ea.y);                                \
      sacc[1][0] = bflo(ea.z); sacc[1][1] = bfhi(ea.z);                                \
      sacc[1][2] = bflo(ea.w); sacc[1][3] = bfhi(ea.w);                                \
      sacc[2][0] = bflo(eb.x); sacc[2][1] = bfhi(eb.x);                                \
      sacc[2][2] = bflo(eb.y); sacc[2][3] = bfhi(eb.y);                                \
      sacc[3][0] = bflo(eb.z); sacc[3][1] = bfhi(eb.z);                                \
      sacc[3][2] = bflo(eb.w); sacc[3][3] = bfhi(eb.w);                                \
      _Pragma("unroll") for (int nt = 0; nt < 4; ++nt)                                 \
        _Pragma("unroll") for (int ks = 0; ks < 2; ++ks)                               \
          sacc[nt] = __builtin_amdgcn_mfma_f32_16x16x32_bf16(bk_[nt][ks], aq[mt][ks],  \
                                                             sacc[nt], 0, 0, 0);       \
      float p[4][4];                                                                   \
      _Pragma("unroll") for (int nt = 0; nt < 4; ++nt)                                 \
        _Pragma("unroll") for (int r = 0; r < 4; ++r)                                  \
          p[nt][r] = __builtin_amdgcn_exp2f(sacc[nt][r]);                              \
      unsigned int wd[8];                                                              \
      _Pragma("unroll") for (int ks = 0; ks < 2; ++ks) {                               \
        wd[ks * 4 + 0] = pack2(p[2 * ks][1],     p[2 * ks][0]);                        \
        wd[ks * 4 + 1] = pack2(p[2 * ks][3],     p[2 * ks][2]);                        \
        wd[ks * 4 + 2] = pack2(p[2 * ks + 1][1], p[2 * ks + 1][0]);                    \
        wd[ks * 4 + 3] = pack2(p[2 * ks + 1][3], p[2 * ks + 1][2]);                    \
        u32x4 uv = {wd[ks * 4], wd[ks * 4 + 1], wd[ks * 4 + 2], wd[ks * 4 + 3]};       \
        ap[mt][ks] = __builtin_bit_cast(bf16x8, uv);                                   \
      }                                                                                \
    }                                                                                  \
    _Pragma("unroll") for (int mt = 0; mt < 2; ++mt) {                                 \
      _Pragma("unroll") for (int nt = 0; nt < 4; ++nt)                                 \
        _Pragma("unroll") for (int ks = 0; ks < 2; ++ks)                               \
          oacc[mt][nt] = __builtin_amdgcn_mfma_f32_16x16x32_bf16(ap[mt][ks], bv[nt][ks],\
                                                                 oacc[mt][nt], 0, 0, 0);\
      _Pragma("unroll") for (int ks = 0; ks < 2; ++ks)                                 \
        liacc[mt] = __builtin_amdgcn_mfma_f32_16x16x32_bf16(ap[mt][ks], bones,         \
                                                            liacc[mt], 0, 0, 0);       \
    }                                                                                  \
  }

#define FITER(KT, CBUF, SBUF, VMC, ISSUE, UA, UB, UC, UD, LA, LB, LC, LD)              \
  {                                                                                    \
    asm volatile("s_waitcnt vmcnt(" VMC ")" ::: "memory");                             \
    __builtin_amdgcn_sched_barrier(0);                                                 \
    asm volatile("s_barrier" ::: "memory");                                            \
    __builtin_amdgcn_sched_barrier(0);                                                 \
    if (ISSUE) {                                                                       \
      const size_t ko = (size_t)((KT) + 2) * 64;                                       \
      async_cp16(kg0 + ko * HDIM, Ks[SBUF] + w * 512);                                 \
      async_cp16(kg1 + ko * HDIM, Ks[SBUF] + (w + 4) * 512);                           \
      async_cp16(vg0 + ko, Vs[SBUF] + w * 512);                                        \
      async_cp16(vg1 + ko, Vs[SBUF] + (w + 4) * 512);                                  \
      lem_load(lemq, LA, LB, LC, LD);                                                  \
      lemq += 8192;                                                                    \
    }                                                                                  \
    FLASH_COMPUTE(CBUF, UA, UB, UC, UD);                                               \
  }

  // main loop: iters 0..29 (all issue kt+2 <= 31); tails 30, 31
  for (int kt = 0; kt < 30; kt += 3) {
    FITER(kt + 0, 0, 2, "8", true,  l00, l01, l02, l03, l20, l21, l22, l23)
    FITER(kt + 1, 1, 0, "8", true,  l10, l11, l12, l13, l00, l01, l02, l03)
    FITER(kt + 2, 2, 1, "8", true,  l20, l21, l22, l23, l10, l11, l12, l13)
  }
  FITER(30, 0, 0, "8", false, l00, l01, l02, l03, l00, l01, l02, l03)
  FITER(31, 1, 0, "0", false, l10, l11, l12, l13, l10, l11, l12, l13)

#undef FITER
#undef FLASH_COMPUTE

  // epilogue: liacc[mt][r] = sum_k P for q = w*32+mt*16+g*4+r (same row layout as oacc)
#pragma unroll
  for (int mt = 0; mt < 2; ++mt) {
#pragma unroll
    for (int r = 0; r < 4; ++r) {
      float inv = 1.0f / liacc[mt][r];
      int qrow = q0 + w * 32 + mt * 16 + g * 4 + r;
#pragma unroll
      for (int nt = 0; nt < 4; ++nt)
        out[((size_t)b * LL + qrow) * 1024 + h * 64 + nt * 16 + cc] = oacc[mt][nt][r] * inv;
    }
  }
}

extern "C" void kernel_launch(void* const* d_in, const int* in_sizes, int n_in,
                              void* d_out, int out_size, void* d_ws, size_t ws_size,
                              hipStream_t stream) {
  const float* x    = (const float*)d_in[0];
  const float* mask = (const float*)d_in[1];
  const float* Wq   = (const float*)d_in[2];
  const float* bq   = (const float*)d_in[3];
  const float* Wk   = (const float*)d_in[4];
  const float* bk   = (const float*)d_in[5];
  const float* Wv   = (const float*)d_in[6];
  const float* bv   = (const float*)d_in[7];
  float* out = (float*)d_out;
  (void)in_sizes; (void)n_in; (void)out_size; (void)ws_size;

  char* ws = (char*)d_ws;
  // layout: qkv @0 (24 MiB); xb @24 (8 MiB); Wt @32 (6 MiB);
  // lem @24 (16 MiB) overlaps xb/Wt — dead after qkv_gemm (same-stream serialization)
  unsigned short* qkv = (unsigned short*)(ws);
  unsigned short* xb  = (unsigned short*)(ws + (24u << 20));
  unsigned short* Wt  = (unsigned short*)(ws + (32u << 20));
  unsigned short* lem = (unsigned short*)(ws + (24u << 20));

  cvt_x_kernel<<<dim3(4096), dim3(256), 0, stream>>>(x, xb);
  transpose_w_kernel<<<dim3(16, 16, 3), dim3(256), 0, stream>>>(Wq, Wk, Wv, Wt);
  qkv_gemm_kernel<<<dim3(8, 32, 3), dim3(256), 0, stream>>>(xb, Wt, bq, bk, bv, qkv);
  lem_prep_kernel<<<dim3(16, 32, 2), dim3(256), 0, stream>>>(mask, lem);
  flash_kernel<<<dim3(16, 32), dim3(256), 0, stream>>>(qkv, qkv + 4194304, qkv + 8388608,
                                                       lem, out);
}

// Round 6
// 193.906 us; speedup vs baseline: 1.1327x; 1.0376x over previous
//
#include <hip/hip_runtime.h>

// B=2, L=2048, DIM=1024, H=16, HD=64; scale folded into Q: 0.125*log2e; mask: -60*log2e
#define LL 2048
#define NHEADS 16
#define HDIM 64
#define QSCALE 0.18033688011112042f   // 0.125 * log2(e)
#define MASKC1 -86.56170245333780f    // -60 * log2(e)

typedef __attribute__((ext_vector_type(8))) __bf16 bf16x8;
typedef __attribute__((ext_vector_type(4))) float f32x4;
typedef __attribute__((ext_vector_type(4))) unsigned int u32x4;

__device__ __forceinline__ unsigned short f2bf(float f) {
  unsigned int u = __builtin_bit_cast(unsigned int, f);
  u += 0x7fffu + ((u >> 16) & 1u);   // RNE
  return (unsigned short)(u >> 16);
}

__device__ __forceinline__ bf16x8 ld_frag(const unsigned short* p) {
  return *reinterpret_cast<const bf16x8*>(p);
}

__device__ __forceinline__ float bflo(unsigned int u) {
  return __builtin_bit_cast(float, u << 16);
}
__device__ __forceinline__ float bfhi(unsigned int u) {
  return __builtin_bit_cast(float, u & 0xffff0000u);
}
// pack two floats (truncated to bf16) into one u32: low short = lo, high short = hi
__device__ __forceinline__ unsigned int pack2(float hi, float lo) {
  return __builtin_amdgcn_perm(__builtin_bit_cast(unsigned int, hi),
                               __builtin_bit_cast(unsigned int, lo), 0x07060302u);
}

// async global->LDS, 16B per lane; LDS dest = wave-uniform base + lane*16
__device__ __forceinline__ void async_cp16(const unsigned short* g, unsigned short* l) {
  __builtin_amdgcn_global_load_lds(
      (const __attribute__((address_space(1))) unsigned int*)(unsigned long long)(g),
      (__attribute__((address_space(3))) unsigned int*)(unsigned int)(unsigned long long)(l),
      16, 0, 0);
}

// 64B lem prefetch via inline asm (keeps compiler's waitcnt bookkeeping out of the
// pipeline; completion is guaranteed by the manual counted vmcnt at ITER top).
__device__ __forceinline__ void lem_load(const unsigned short* p, uint4& a, uint4& b,
                                         uint4& c, uint4& d) {
  asm volatile("global_load_dwordx4 %0, %4, off\n\t"
               "global_load_dwordx4 %1, %4, off offset:16\n\t"
               "global_load_dwordx4 %2, %4, off offset:32\n\t"
               "global_load_dwordx4 %3, %4, off offset:48"
               : "=&v"(a), "=&v"(b), "=&v"(c), "=&v"(d)
               : "v"(p)
               : "memory");
}

// ---------------- prep: fp32 -> bf16 convert of x ----------------
__global__ __launch_bounds__(256) void cvt_x_kernel(const float* __restrict__ x,
                                                    unsigned short* __restrict__ xb) {
  int i = (blockIdx.x * 256 + threadIdx.x) * 4;
  float4 v = *reinterpret_cast<const float4*>(x + i);
  ushort4 o;
  o.x = f2bf(v.x); o.y = f2bf(v.y); o.z = f2bf(v.z); o.w = f2bf(v.w);
  *reinterpret_cast<ushort4*>(xb + i) = o;
}

// ---------------- prep: W [K][N] fp32 -> Wt [N][K] bf16 ----------------
__global__ __launch_bounds__(256) void transpose_w_kernel(const float* __restrict__ Wq,
                                                          const float* __restrict__ Wk,
                                                          const float* __restrict__ Wv,
                                                          unsigned short* __restrict__ WtAll) {
  int z = blockIdx.z;
  const float* W = (z == 0) ? Wq : (z == 1) ? Wk : Wv;
  unsigned short* dst = WtAll + (size_t)z * 1024 * 1024;
  int n0 = blockIdx.x * 64, k0 = blockIdx.y * 64;
  __shared__ float t[64][65];
  int tx = threadIdx.x & 63, ty = threadIdx.x >> 6;
#pragma unroll
  for (int p = 0; p < 16; ++p) {
    int kr = p * 4 + ty;
    t[kr][tx] = W[(size_t)(k0 + kr) * 1024 + n0 + tx];
  }
  __syncthreads();
#pragma unroll
  for (int p = 0; p < 16; ++p) {
    int nr = p * 4 + ty;
    dst[(size_t)(n0 + nr) * 1024 + k0 + tx] = f2bf(t[tx][nr]);
  }
}

// ---------------- prep: lem = bf16(mask*MASKC1), per-flash-thread packed ----------------
// Output layout [b][qb(16)][kt(32)][tid(256)][32 shorts = 64B]; 32 shorts ordered
// idx = mt*16 + nt*4 + r  for value lem[q = qb*128 + w*32 + mt*16 + cc][k = kt*64 + nt*16 + g*4 + r].
__global__ __launch_bounds__(256) void lem_prep_kernel(const float* __restrict__ mask,
                                                       unsigned short* __restrict__ lem) {
  const int qb = blockIdx.x, kt = blockIdx.y, b = blockIdx.z;
  const int tid = threadIdx.x;
  __shared__ unsigned short lds[128 * 72];
  {
    const int r0 = tid >> 4;          // 0..15
    const int c0 = (tid & 15) * 4;    // 0..60
#pragma unroll
    for (int p = 0; p < 8; ++p) {
      int row = p * 16 + r0;
      float4 v = *reinterpret_cast<const float4*>(
          mask + ((size_t)b * LL + qb * 128 + row) * LL + kt * 64 + c0);
      ushort4 o;
      o.x = f2bf(v.x * MASKC1); o.y = f2bf(v.y * MASKC1);
      o.z = f2bf(v.z * MASKC1); o.w = f2bf(v.w * MASKC1);
      *reinterpret_cast<ushort4*>(&lds[row * 72 + c0]) = o;
    }
  }
  __syncthreads();
  const int w = tid >> 6, lane = tid & 63, g = lane >> 4, cc = lane & 15;
  unsigned int ow[16];
#pragma unroll
  for (int mt = 0; mt < 2; ++mt) {
    const int q = w * 32 + mt * 16 + cc;
#pragma unroll
    for (int nt = 0; nt < 4; ++nt) {
      uint2 v = *reinterpret_cast<const uint2*>(&lds[q * 72 + nt * 16 + g * 4]);
      ow[mt * 8 + nt * 2]     = v.x;   // r0 (lo), r1 (hi)
      ow[mt * 8 + nt * 2 + 1] = v.y;   // r2 (lo), r3 (hi)
    }
  }
  uint4* dst = reinterpret_cast<uint4*>(
      lem + ((((size_t)b * 16 + qb) * 32 + kt) * 256 + tid) * 32);
#pragma unroll
  for (int j = 0; j < 4; ++j)
    dst[j] = make_uint4(ow[4 * j], ow[4 * j + 1], ow[4 * j + 2], ow[4 * j + 3]);
}

// ---------------- QKV projection GEMM (T3/T4 counted-vmcnt, 3-buffer, BK=32) ----------------
// grid (8, 32, 3). z==0: Q bf16 [bh][l][d] * QSCALE; z==1: K; z==2: V^T [bh][d][pos], key-permuted.
// LDS layout per buffer (A and B each 128x32 bf16 = 8KB): logical row-pairs form 128B
// pseudo-rows (pr = r>>1); 16B chunk slot s = (pr + (r&1)*4 + c) & 7 -- same bank
// distribution as the proven BK=64 rotation (8 lanes per slot-group, distinct rows).
// Staging source is the inverse permutation (both-sides-or-neither).
__global__ __launch_bounds__(256) void qkv_gemm_kernel(
    const unsigned short* __restrict__ xb, const unsigned short* __restrict__ WtAll,
    const float* __restrict__ bq, const float* __restrict__ bk, const float* __restrict__ bv,
    unsigned short* __restrict__ qkv) {
  const int z = blockIdx.z;
  const unsigned short* Wt = WtAll + (size_t)z * 1024 * 1024;
  const float* bias = (z == 0) ? bq : (z == 1) ? bk : bv;
  unsigned short* outb = qkv + (size_t)z * 4194304;

  // A buffers: smem + buf*4096; B buffers: smem + 12288 + buf*4096 (shorts). 48 KB total.
  __shared__ __align__(16) unsigned short smem[24576];

  const int tid = threadIdx.x;
  const int w = tid >> 6, lane = tid & 63, g = lane >> 4, cc = lane & 15;
  const int wm = w >> 1, wn = w & 1;
  const int m0 = blockIdx.y * 128, n0 = blockIdx.x * 128;

  // staging source coords: wave w, call i covers pseudo-rows w*16+i*8 .. +8
  const int prl = lane >> 3, sl = lane & 7;
  int r0g, c0g, r1g, c1g;
  {
    int pr0 = w * 16 + prl;       int j0 = (sl - pr0) & 7;
    r0g = 2 * pr0 + (j0 >> 2);    c0g = j0 & 3;
    int pr1 = w * 16 + 8 + prl;   int j1 = (sl - pr1) & 7;
    r1g = 2 * pr1 + (j1 >> 2);    c1g = j1 & 3;
  }
  const unsigned short* gaA0 = xb + (size_t)(m0 + r0g) * 1024 + c0g * 8;
  const unsigned short* gaA1 = xb + (size_t)(m0 + r1g) * 1024 + c1g * 8;
  const unsigned short* gbB0 = Wt + (size_t)(n0 + r0g) * 1024 + c0g * 8;
  const unsigned short* gbB1 = Wt + (size_t)(n0 + r1g) * 1024 + c1g * 8;

  // read-side: A row R = wm*64 + mt*16 + cc -> pr = wm*32 + (cc>>1) + 8*mt,
  // slot s = ((cc>>1) + (cc&1)*4 + g) & 7 (mt-independent)
  const int praB = wm * 32 + (cc >> 1);
  const int prbB = wn * 32 + (cc >> 1);
  const int sab = ((cc >> 1) + (cc & 1) * 4 + g) & 7;

  f32x4 acc[4][4];
#pragma unroll
  for (int i = 0; i < 4; ++i)
#pragma unroll
    for (int j = 0; j < 4; ++j) acc[i][j] = (f32x4)0.0f;

  // prologue: stage k-tiles 0 -> buf0, 1 -> buf1 (4 VMEM ops each)
  async_cp16(gaA0, smem + w * 1024);
  async_cp16(gaA1, smem + w * 1024 + 512);
  async_cp16(gbB0, smem + 12288 + w * 1024);
  async_cp16(gbB1, smem + 12288 + w * 1024 + 512);
  async_cp16(gaA0 + 32, smem + 4096 + w * 1024);
  async_cp16(gaA1 + 32, smem + 4096 + w * 1024 + 512);
  async_cp16(gbB0 + 32, smem + 12288 + 4096 + w * 1024);
  async_cp16(gbB1 + 32, smem + 12288 + 4096 + w * 1024 + 512);

#define GITER(KT, CBUF, SBUF, VMC, ISSUE)                                              \
  {                                                                                    \
    asm volatile("s_waitcnt vmcnt(" VMC ")" ::: "memory");                             \
    __builtin_amdgcn_sched_barrier(0);                                                 \
    asm volatile("s_barrier" ::: "memory");                                            \
    __builtin_amdgcn_sched_barrier(0);                                                 \
    if (ISSUE) {                                                                       \
      async_cp16(gaA0 + ((KT) + 2) * 32, smem + (SBUF) * 4096 + w * 1024);             \
      async_cp16(gaA1 + ((KT) + 2) * 32, smem + (SBUF) * 4096 + w * 1024 + 512);       \
      async_cp16(gbB0 + ((KT) + 2) * 32, smem + 12288 + (SBUF) * 4096 + w * 1024);     \
      async_cp16(gbB1 + ((KT) + 2) * 32, smem + 12288 + (SBUF) * 4096 + w * 1024 + 512);\
    }                                                                                  \
    {                                                                                  \
      const unsigned short* Ab = smem + (CBUF) * 4096;                                 \
      const unsigned short* Bb = smem + 12288 + (CBUF) * 4096;                         \
      bf16x8 af[4], bfr[4];                                                            \
      _Pragma("unroll") for (int mt = 0; mt < 4; ++mt)                                 \
        af[mt] = ld_frag(&Ab[(praB + 8 * mt) * 64 + sab * 8]);                         \
      _Pragma("unroll") for (int nt = 0; nt < 4; ++nt)                                 \
        bfr[nt] = ld_frag(&Bb[(prbB + 8 * nt) * 64 + sab * 8]);                        \
      _Pragma("unroll") for (int mt = 0; mt < 4; ++mt)                                 \
        _Pragma("unroll") for (int nt = 0; nt < 4; ++nt)                               \
          acc[mt][nt] = __builtin_amdgcn_mfma_f32_16x16x32_bf16(af[mt], bfr[nt],       \
                                                                acc[mt][nt], 0, 0, 0); \
    }                                                                                  \
  }

  for (int kt = 0; kt < 30; kt += 3) {
    GITER(kt + 0, 0, 2, "4", true)
    GITER(kt + 1, 1, 0, "4", true)
    GITER(kt + 2, 2, 1, "4", true)
  }
  GITER(30, 0, 0, "4", false)
  GITER(31, 1, 0, "0", false)

#undef GITER

  if (z != 2) {
    const float sc = (z == 0) ? QSCALE : 1.0f;
#pragma unroll
    for (int nt = 0; nt < 4; ++nt) {
      int n = n0 + wn * 64 + nt * 16 + cc;
      float bval = bias[n];
      int h = n >> 6, d = n & 63;
#pragma unroll
      for (int mt = 0; mt < 4; ++mt) {
#pragma unroll
        for (int r = 0; r < 4; ++r) {
          int m = m0 + wm * 64 + mt * 16 + g * 4 + r;
          int b = m >> 11, l = m & 2047;
          outb[(((size_t)(b * NHEADS + h) * LL) + l) * HDIM + d] =
              f2bf((acc[mt][nt][r] + bval) * sc);
        }
      }
    }
  } else {
    // V^T epilogue with key permutation: key6 = mt*16 + g*4 + r
    // -> pos = (mt>>1)*32 + g*8 + (mt&1)*4 + r   (inverse of flash's in-register P layout)
    __syncthreads();
#pragma unroll
    for (int nt = 0; nt < 4; ++nt) {
      int nr = wn * 64 + nt * 16 + cc;
      float bval = bias[n0 + nr];
#pragma unroll
      for (int mt = 0; mt < 4; ++mt)
#pragma unroll
        for (int r = 0; r < 4; ++r)
          smem[nr * 128 + wm * 64 + (mt >> 1) * 32 + g * 8 + (mt & 1) * 4 + r] =
              f2bf(acc[mt][nt][r] + bval);
    }
    __syncthreads();
    int row = tid >> 1, half = tid & 1;
    int n = n0 + row, hh = n >> 6, dd = n & 63;
    int bb = m0 >> 11, l0 = (m0 & 2047) + half * 64;
    unsigned short* dst = outb + ((size_t)(bb * NHEADS + hh) * HDIM + dd) * LL + l0;
#pragma unroll
    for (int i = 0; i < 8; ++i)
      *reinterpret_cast<uint4*>(dst + i * 8) =
          *reinterpret_cast<const uint4*>(&smem[row * 128 + half * 64 + i * 8]);
  }
}

// ---------------- flash attention ----------------
// grid (16, 32): q-tile 128, 4 waves x 32 q-rows, 2 blocks/CU. Swapped QK^T; P packed
// in-register into PV A-frags (key-permuted V^T); lem folded into MFMA C-init.
// T3/T4 schedule: 3 LDS buffers, stage(kt+2) each iter (4 cp16 + 4 asm lem = 8 VMEM),
// raw s_barrier with COUNTED s_waitcnt vmcnt(8). li via ones-MFMA.
__global__ __launch_bounds__(256, 2) void flash_kernel(
    const unsigned short* __restrict__ Qb, const unsigned short* __restrict__ Kb,
    const unsigned short* __restrict__ Vt, const unsigned short* __restrict__ Lem,
    float* __restrict__ out) {
  const int id = blockIdx.y * 16 + blockIdx.x;   // 512 blocks
  const int nid = (id & 7) * 64 + (id >> 3);     // bijective XCD swizzle (512 % 8 == 0)
  const int qb = nid & 15, bh = nid >> 4;
  const int b = bh >> 4, h = bh & 15;
  const int q0 = qb * 128;
  const int tid = threadIdx.x, w = tid >> 6, lane = tid & 63, g = lane >> 4, cc = lane & 15;
  const size_t bhoff = (size_t)bh * LL * HDIM;

  __shared__ __align__(16) unsigned short Ks[3][64 * 64];  // [key][d], swizzled chunks
  __shared__ __align__(16) unsigned short Vs[3][64 * 64];  // [d][pos], swizzled chunks

  bf16x8 aq[2][2];
#pragma unroll
  for (int mt = 0; mt < 2; ++mt)
#pragma unroll
    for (int ks = 0; ks < 2; ++ks)
      aq[mt][ks] = *reinterpret_cast<const bf16x8*>(
          Qb + bhoff + (size_t)(q0 + w * 32 + mt * 16 + cc) * HDIM + ks * 32 + g * 8);

  const int srow = lane >> 3;
  const int gcs = ((lane & 7) - srow) & 7;
  const unsigned short* kg0 = Kb + bhoff + (size_t)(w * 8 + srow) * HDIM + gcs * 8;
  const unsigned short* kg1 = Kb + bhoff + (size_t)(32 + w * 8 + srow) * HDIM + gcs * 8;
  const unsigned short* vg0 = Vt + bhoff + (size_t)(w * 8 + srow) * LL + gcs * 8;
  const unsigned short* vg1 = Vt + bhoff + (size_t)(32 + w * 8 + srow) * LL + gcs * 8;

  const unsigned short* lemq = Lem + (((size_t)b * 16 + qb) * 32 * 256 + tid) * 32;

  const u32x4 onesu = {0x3F803F80u, 0x3F803F80u, 0x3F803F80u, 0x3F803F80u};
  const bf16x8 bones = __builtin_bit_cast(bf16x8, onesu);

  uint4 l00, l01, l02, l03, l10, l11, l12, l13, l20, l21, l22, l23;

  f32x4 liacc[2];
  f32x4 oacc[2][4];
#pragma unroll
  for (int mt = 0; mt < 2; ++mt) {
    liacc[mt] = (f32x4)0.0f;
#pragma unroll
    for (int nt = 0; nt < 4; ++nt) oacc[mt][nt] = (f32x4)0.0f;
  }

  async_cp16(kg0, Ks[0] + w * 512);
  async_cp16(kg1, Ks[0] + (w + 4) * 512);
  async_cp16(vg0, Vs[0] + w * 512);
  async_cp16(vg1, Vs[0] + (w + 4) * 512);
  lem_load(lemq, l00, l01, l02, l03);
  lemq += 8192;
  async_cp16(kg0 + (size_t)64 * HDIM, Ks[1] + w * 512);
  async_cp16(kg1 + (size_t)64 * HDIM, Ks[1] + (w + 4) * 512);
  async_cp16(vg0 + 64, Vs[1] + w * 512);
  async_cp16(vg1 + 64, Vs[1] + (w + 4) * 512);
  lem_load(lemq, l10, l11, l12, l13);
  lemq += 8192;

#define FLASH_COMPUTE(BUF, LSA, LSB, LSC, LSD)                                         \
  {                                                                                    \
    bf16x8 bk_[4][2], bv[4][2];                                                        \
    _Pragma("unroll") for (int nt = 0; nt < 4; ++nt)                                   \
      _Pragma("unroll") for (int ks = 0; ks < 2; ++ks)                                 \
        bk_[nt][ks] =                                                                  \
            ld_frag(&Ks[BUF][(nt * 16 + cc) * 64 + ((4 * ks + g + cc) & 7) * 8]);      \
    _Pragma("unroll") for (int nt = 0; nt < 4; ++nt)                                   \
      _Pragma("unroll") for (int ks = 0; ks < 2; ++ks)                                 \
        bv[nt][ks] =                                                                   \
            ld_frag(&Vs[BUF][(nt * 16 + cc) * 64 + ((4 * ks + g + cc) & 7) * 8]);      \
    bf16x8 ap[2][2];                                                                   \
    _Pragma("unroll") for (int mt = 0; mt < 2; ++mt) {                                 \
      f32x4 sacc[4];                                                                   \
      const uint4 ea = (mt == 0) ? LSA : LSC;                                          \
      const uint4 eb = (mt == 0) ? LSB : LSD;                                          \
      sacc[0][0] = bflo(ea.x); sacc[0][1] = bfhi(ea.x);                                \
      sacc[0][2] = bflo(ea.y); sacc[0][3] = bfhi(ea.y);                                \
      sacc[1][0] = bflo(ea.z); sacc[1][1] = bfhi(ea.z);                                \
      sacc[1][2] = bflo(ea.w); sacc[1][3] = bfhi(ea.w);                                \
      sacc[2][0] = bflo(eb.x); sacc[2][1] = bfhi(eb.x);                                \
      sacc[2][2] = bflo(eb.y); sacc[2][3] = bfhi(eb.y);                                \
      sacc[3][0] = bflo(eb.z); sacc[3][1] = bfhi(eb.z);                                \
      sacc[3][2] = bflo(eb.w); sacc[3][3] = bfhi(eb.w);                                \
      _Pragma("unroll") for (int nt = 0; nt < 4; ++nt)                                 \
        _Pragma("unroll") for (int ks = 0; ks < 2; ++ks)                               \
          sacc[nt] = __builtin_amdgcn_mfma_f32_16x16x32_bf16(bk_[nt][ks], aq[mt][ks],  \
                                                             sacc[nt], 0, 0, 0);       \
      float p[4][4];                                                                   \
      _Pragma("unroll") for (int nt = 0; nt < 4; ++nt)                                 \
        _Pragma("unroll") for (int r = 0; r < 4; ++r)                                  \
          p[nt][r] = __builtin_amdgcn_exp2f(sacc[nt][r]);                              \
      unsigned int wd[8];                                                              \
      _Pragma("unroll") for (int ks = 0; ks < 2; ++ks) {                               \
        wd[ks * 4 + 0] = pack2(p[2 * ks][1],     p[2 * ks][0]);                        \
        wd[ks * 4 + 1] = pack2(p[2 * ks][3],     p[2 * ks][2]);                        \
        wd[ks * 4 + 2] = pack2(p[2 * ks + 1][1], p[2 * ks + 1][0]);                    \
        wd[ks * 4 + 3] = pack2(p[2 * ks + 1][3], p[2 * ks + 1][2]);                    \
        u32x4 uv = {wd[ks * 4], wd[ks * 4 + 1], wd[ks * 4 + 2], wd[ks * 4 + 3]};       \
        ap[mt][ks] = __builtin_bit_cast(bf16x8, uv);                                   \
      }                                                                                \
    }                                                                                  \
    _Pragma("unroll") for (int mt = 0; mt < 2; ++mt) {                                 \
      _Pragma("unroll") for (int nt = 0; nt < 4; ++nt)                                 \
        _Pragma("unroll") for (int ks = 0; ks < 2; ++ks)                               \
          oacc[mt][nt] = __builtin_amdgcn_mfma_f32_16x16x32_bf16(ap[mt][ks], bv[nt][ks],\
                                                                 oacc[mt][nt], 0, 0, 0);\
      _Pragma("unroll") for (int ks = 0; ks < 2; ++ks)                                 \
        liacc[mt] = __builtin_amdgcn_mfma_f32_16x16x32_bf16(ap[mt][ks], bones,         \
                                                            liacc[mt], 0, 0, 0);       \
    }                                                                                  \
  }

#define FITER(KT, CBUF, SBUF, VMC, ISSUE, UA, UB, UC, UD, LA, LB, LC, LD)              \
  {                                                                                    \
    asm volatile("s_waitcnt vmcnt(" VMC ")" ::: "memory");                             \
    __builtin_amdgcn_sched_barrier(0);                                                 \
    asm volatile("s_barrier" ::: "memory");                                            \
    __builtin_amdgcn_sched_barrier(0);                                                 \
    if (ISSUE) {                                                                       \
      const size_t ko = (size_t)((KT) + 2) * 64;                                       \
      async_cp16(kg0 + ko * HDIM, Ks[SBUF] + w * 512);                                 \
      async_cp16(kg1 + ko * HDIM, Ks[SBUF] + (w + 4) * 512);                           \
      async_cp16(vg0 + ko, Vs[SBUF] + w * 512);                                        \
      async_cp16(vg1 + ko, Vs[SBUF] + (w + 4) * 512);                                  \
      lem_load(lemq, LA, LB, LC, LD);                                                  \
      lemq += 8192;                                                                    \
    }                                                                                  \
    FLASH_COMPUTE(CBUF, UA, UB, UC, UD);                                               \
  }

  for (int kt = 0; kt < 30; kt += 3) {
    FITER(kt + 0, 0, 2, "8", true,  l00, l01, l02, l03, l20, l21, l22, l23)
    FITER(kt + 1, 1, 0, "8", true,  l10, l11, l12, l13, l00, l01, l02, l03)
    FITER(kt + 2, 2, 1, "8", true,  l20, l21, l22, l23, l10, l11, l12, l13)
  }
  FITER(30, 0, 0, "8", false, l00, l01, l02, l03, l00, l01, l02, l03)
  FITER(31, 1, 0, "0", false, l10, l11, l12, l13, l10, l11, l12, l13)

#undef FITER
#undef FLASH_COMPUTE

#pragma unroll
  for (int mt = 0; mt < 2; ++mt) {
#pragma unroll
    for (int r = 0; r < 4; ++r) {
      float inv = 1.0f / liacc[mt][r];
      int qrow = q0 + w * 32 + mt * 16 + g * 4 + r;
#pragma unroll
      for (int nt = 0; nt < 4; ++nt)
        out[((size_t)b * LL + qrow) * 1024 + h * 64 + nt * 16 + cc] = oacc[mt][nt][r] * inv;
    }
  }
}

extern "C" void kernel_launch(void* const* d_in, const int* in_sizes, int n_in,
                              void* d_out, int out_size, void* d_ws, size_t ws_size,
                              hipStream_t stream) {
  const float* x    = (const float*)d_in[0];
  const float* mask = (const float*)d_in[1];
  const float* Wq   = (const float*)d_in[2];
  const float* bq   = (const float*)d_in[3];
  const float* Wk   = (const float*)d_in[4];
  const float* bk   = (const float*)d_in[5];
  const float* Wv   = (const float*)d_in[6];
  const float* bv   = (const float*)d_in[7];
  float* out = (float*)d_out;
  (void)in_sizes; (void)n_in; (void)out_size; (void)ws_size;

  char* ws = (char*)d_ws;
  // layout: qkv @0 (24 MiB); xb @24 (8 MiB); Wt @32 (6 MiB);
  // lem @24 (16 MiB) overlaps xb/Wt — dead after qkv_gemm (same-stream serialization)
  unsigned short* qkv = (unsigned short*)(ws);
  unsigned short* xb  = (unsigned short*)(ws + (24u << 20));
  unsigned short* Wt  = (unsigned short*)(ws + (32u << 20));
  unsigned short* lem = (unsigned short*)(ws + (24u << 20));

  cvt_x_kernel<<<dim3(4096), dim3(256), 0, stream>>>(x, xb);
  transpose_w_kernel<<<dim3(16, 16, 3), dim3(256), 0, stream>>>(Wq, Wk, Wv, Wt);
  qkv_gemm_kernel<<<dim3(8, 32, 3), dim3(256), 0, stream>>>(xb, Wt, bq, bk, bv, qkv);
  lem_prep_kernel<<<dim3(16, 32, 2), dim3(256), 0, stream>>>(mask, lem);
  flash_kernel<<<dim3(16, 32), dim3(256), 0, stream>>>(qkv, qkv + 4194304, qkv + 8388608,
                                                       lem, out);
}